// Round 4
// baseline (4600.708 us; speedup 1.0000x reference)
//
#include <hip/hip_runtime.h>
#include <math.h>

typedef long long ll;
typedef __attribute__((ext_vector_type(8))) short short8;
typedef __attribute__((ext_vector_type(4))) float f32x4;

#define NBATCH 4
#define TSEQ   4095
#define NTOK   4096
#define DMODEL 512
#define NHEAD  8
#define DHEAD  64
#define NLAND  256
#define INDIM  1024
#define KCONV  33
#define NBH    32
#define NSPLIT 8

// ---------------- helpers ----------------
__device__ __forceinline__ float bred(float* red, float v, int tid, int op){
  red[tid] = v; __syncthreads();
  for (int s = 128; s > 0; s >>= 1){
    if (tid < s) red[tid] = op ? fmaxf(red[tid], red[tid+s]) : (red[tid] + red[tid+s]);
    __syncthreads();
  }
  float r = red[0];
  __syncthreads();
  return r;
}

__device__ __forceinline__ short f2bf(float f){  // RNE f32->bf16
  unsigned u = __float_as_uint(f);
  u += 0x7fff + ((u>>16)&1);
  return (short)(u>>16);
}

// ---------------- PE table ----------------
__global__ __launch_bounds__(256) void pe_table_k(float* __restrict__ pe){
  int idx = blockIdx.x*256 + threadIdx.x;
  if (idx >= TSEQ*DMODEL) return;
  int c = idx & 511; int t = idx >> 9;
  const double NEG = -9.210340371976184 / 512.0;
  double div = exp((double)(c & ~1) * NEG);
  double ang = (double)t * div;
  pe[idx] = (c & 1) ? (float)cos(ang) : (float)sin(ang);
}

__global__ __launch_bounds__(256) void pe_cls_add_k(float* __restrict__ hb, const float* __restrict__ cls,
                                                    const float* __restrict__ pe){
  ll idx = (ll)blockIdx.x*256 + threadIdx.x;
  int c = (int)(idx & 511);
  ll rn = idx >> 9;
  int n = (int)(rn & 4095);
  if (n == 0) hb[idx] = cls[c];
  else        hb[idx] += pe[(ll)(n-1)*512 + c];
}

// ---------------- LayerNorm rows (D=512) ----------------
__global__ __launch_bounds__(256) void ln_rows_k(const float* __restrict__ in, float* __restrict__ out,
                                                 const float* __restrict__ sc, const float* __restrict__ bi){
  __shared__ float red[256];
  ll row = blockIdx.x;
  const float* xr = in + row*DMODEL;
  float* orow = out + row*DMODEL;
  int tid = threadIdx.x;
  float v0 = xr[tid], v1 = xr[tid+256];
  float mu = bred(red, v0+v1, tid, 0) * (1.f/512.f);
  float d0 = v0-mu, d1 = v1-mu;
  float var = bred(red, d0*d0 + d1*d1, tid, 0) * (1.f/512.f);
  float inv = 1.f / sqrtf(var + 1e-5f);
  orow[tid]     = d0*inv*sc[tid]     + bi[tid];
  orow[tid+256] = d1*inv*sc[tid+256] + bi[tid+256];
}

// ============ bf16 MFMA GEMM (big dense layers + y2) ============
template<int BM, int BN>
__global__ __launch_bounds__(256)
void mgemm(const float* __restrict__ A, const float* __restrict__ Bm,
           float* __restrict__ C, const float* __restrict__ E,
           const float* __restrict__ bias,
           int Mr, int K, int lda, int ldb, int ldc,
           ll sA, ll sB, ll sC,
           float c0, float c1, int flags)
{
  constexpr int MI = BM/32, NJ = BN/32;
  __shared__ __align__(16) short As[BM*64];
  __shared__ __align__(16) short Bs[BN*64];
  int z = blockIdx.z;
  A += (ll)z*sA; Bm += (ll)z*sB; C += (ll)z*sC;
  if (E) E += (ll)z*sC;
  int n0 = blockIdx.x*BN, m0 = blockIdx.y*BM;
  int tid = threadIdx.x;
  int lane = tid & 63, w = tid >> 6;
  int wr = w >> 1, wc = w & 1;
  int l15 = lane & 15, l4 = lane >> 4;

  f32x4 acc[MI][NJ];
  #pragma unroll
  for (int i = 0; i < MI; i++)
    #pragma unroll
    for (int j = 0; j < NJ; j++) acc[i][j] = (f32x4){0.f,0.f,0.f,0.f};

  for (int k0 = 0; k0 < K; k0 += 64){
    #pragma unroll
    for (int it = 0; it < BM/32; ++it){
      int tau = tid + 256*it;
      int row = tau >> 3, slot = tau & 7;
      int grow = m0 + row;
      f32x4 p0 = {0.f,0.f,0.f,0.f}, p1 = {0.f,0.f,0.f,0.f};
      if (grow < Mr){
        const float* ap = A + (ll)grow*lda + k0 + slot*8;
        p0 = *(const f32x4*)ap; p1 = *(const f32x4*)(ap+4);
      }
      short8 v;
      v[0]=f2bf(p0[0]); v[1]=f2bf(p0[1]); v[2]=f2bf(p0[2]); v[3]=f2bf(p0[3]);
      v[4]=f2bf(p1[0]); v[5]=f2bf(p1[1]); v[6]=f2bf(p1[2]); v[7]=f2bf(p1[3]);
      ((short8*)As)[row*8 + (slot ^ (row&7))] = v;
    }
    #pragma unroll
    for (int it = 0; it < BN/32; ++it){
      int tau = tid + 256*it;
      int n = tau & (BN-1), slot = tau >> (BN==128 ? 7 : 6);
      const float* bp = Bm + (ll)(k0 + slot*8)*ldb + n0 + n;
      short8 v;
      #pragma unroll
      for (int i = 0; i < 8; i++) v[i] = f2bf(bp[(ll)i*ldb]);
      ((short8*)Bs)[n*8 + (slot ^ (n&7))] = v;
    }
    __syncthreads();
    #pragma unroll
    for (int kc = 0; kc < 2; kc++){
      short8 af[MI], bf[NJ];
      #pragma unroll
      for (int i = 0; i < MI; i++){
        int row = wr*(BM/2) + i*16 + l15;
        int g = kc*4 + l4;
        af[i] = ((short8*)As)[row*8 + (g ^ (row&7))];
      }
      #pragma unroll
      for (int j = 0; j < NJ; j++){
        int col = wc*(BN/2) + j*16 + l15;
        int g = kc*4 + l4;
        bf[j] = ((short8*)Bs)[col*8 + (g ^ (col&7))];
      }
      #pragma unroll
      for (int i = 0; i < MI; i++)
        #pragma unroll
        for (int j = 0; j < NJ; j++)
          acc[i][j] = __builtin_amdgcn_mfma_f32_16x16x32_bf16(af[i], bf[j], acc[i][j], 0, 0, 0);
    }
    __syncthreads();
  }

  #pragma unroll
  for (int i = 0; i < MI; i++){
    int rbase = m0 + wr*(BM/2) + i*16 + l4*4;
    #pragma unroll
    for (int j = 0; j < NJ; j++){
      int col = n0 + wc*(BN/2) + j*16 + l15;
      #pragma unroll
      for (int r = 0; r < 4; r++){
        int m = rbase + r;
        if (m >= Mr) continue;
        float v = acc[i][j][r];
        if (flags & 4) v = c0 * E[(ll)m*ldc + col] + c1 * v;
        if (flags & 1) v += bias[col];
        if (flags & 2) v = fmaxf(v, 0.f);
        int om = (flags & 16) ? (m + m/TSEQ + 1) : m;
        ll ci = (ll)om*ldc + col;
        if (flags & 8) v += C[ci];
        C[ci] = v;
      }
    }
  }
}

// ---------------- NT GEMM fp32 (attn2 scores only) ----------------
__global__ __launch_bounds__(256)
void gemm_nt(const float* __restrict__ A, const float* __restrict__ Bm, float* __restrict__ C,
             int lda, int ldb, int ldc,
             ll sAb, ll sAh, ll sBb, ll sBh, ll sCb, ll sCh,
             float alpha)
{
  __shared__ float As[64][65];
  __shared__ float Bs[64][65];
  int z = blockIdx.z; int b = z >> 3; int h = z & 7;
  A  += (ll)b*sAb + (ll)h*sAh;
  Bm += (ll)b*sBb + (ll)h*sBh;
  C  += (ll)b*sCb + (ll)h*sCh;
  int n0 = blockIdx.x*64, m0 = blockIdx.y*64;
  int tid = threadIdx.x;
  int kk = tid & 63, rr = tid >> 6;
  #pragma unroll
  for (int r = 0; r < 16; r++){
    As[rr + 4*r][kk] = A [(ll)(m0 + rr + 4*r)*lda + kk];
    Bs[rr + 4*r][kk] = Bm[(ll)(n0 + rr + 4*r)*ldb + kk];
  }
  __syncthreads();
  int tx = tid & 15, ty = tid >> 4;
  float acc[4][4] = {};
  for (int k = 0; k < 64; k++){
    float a[4], bv[4];
    #pragma unroll
    for (int i = 0; i < 4; i++) a[i] = As[ty + 16*i][k];
    #pragma unroll
    for (int j = 0; j < 4; j++) bv[j] = Bs[tx + 16*j][k];
    #pragma unroll
    for (int i = 0; i < 4; i++)
      #pragma unroll
      for (int j = 0; j < 4; j++)
        acc[i][j] += a[i]*bv[j];
  }
  #pragma unroll
  for (int i = 0; i < 4; i++)
    #pragma unroll
    for (int j = 0; j < 4; j++)
      C[(ll)(m0 + ty + 16*i)*ldc + n0 + tx + 16*j] = alpha * acc[i][j];
}

// ================= fused Newton-Schulz pinv: one block per bh =================
__device__ __forceinline__ void bgemm256(const float* __restrict__ A, const float* __restrict__ B,
    float* __restrict__ C, const float* __restrict__ E, float c0, float c1,
    short* As, short* Bs, int tid)
{
  int lane = tid & 63, w = tid >> 6;
  int l15 = lane & 15, l4 = lane >> 4;
  for (int rb = 0; rb < 4; rb++){
    f32x4 acc[4][4];
    #pragma unroll
    for (int i = 0; i < 4; i++)
      #pragma unroll
      for (int j = 0; j < 4; j++) acc[i][j] = (f32x4){0.f,0.f,0.f,0.f};
    for (int kc64 = 0; kc64 < 4; kc64++){
      __syncthreads();
      #pragma unroll
      for (int it = 0; it < 2; it++){
        int tau = tid + 256*it;
        int row = tau >> 3, slot = tau & 7;
        const float* ap = A + (ll)(rb*64 + row)*256 + kc64*64 + slot*8;
        f32x4 p0 = *(const f32x4*)ap, p1 = *(const f32x4*)(ap+4);
        short8 v;
        v[0]=f2bf(p0[0]); v[1]=f2bf(p0[1]); v[2]=f2bf(p0[2]); v[3]=f2bf(p0[3]);
        v[4]=f2bf(p1[0]); v[5]=f2bf(p1[1]); v[6]=f2bf(p1[2]); v[7]=f2bf(p1[3]);
        ((short8*)As)[row*8 + (slot ^ (row&7))] = v;
      }
      #pragma unroll
      for (int it = 0; it < 8; it++){
        int tau = tid + 256*it;
        int col = tau & 255, slot = tau >> 8;
        const float* bp = B + (ll)(kc64*64 + slot*8)*256 + col;
        short8 v;
        #pragma unroll
        for (int i = 0; i < 8; i++) v[i] = f2bf(bp[(ll)i*256]);
        ((short8*)Bs)[col*8 + (slot ^ (col&7))] = v;
      }
      __syncthreads();
      #pragma unroll
      for (int kc = 0; kc < 2; kc++){
        short8 af[4], bf[4];
        #pragma unroll
        for (int i = 0; i < 4; i++){
          int row = i*16 + l15;
          int g = kc*4 + l4;
          af[i] = ((short8*)As)[row*8 + (g ^ (row&7))];
        }
        #pragma unroll
        for (int j = 0; j < 4; j++){
          int col = w*64 + j*16 + l15;
          int g = kc*4 + l4;
          bf[j] = ((short8*)Bs)[col*8 + (g ^ (col&7))];
        }
        #pragma unroll
        for (int i = 0; i < 4; i++)
          #pragma unroll
          for (int j = 0; j < 4; j++)
            acc[i][j] = __builtin_amdgcn_mfma_f32_16x16x32_bf16(af[i], bf[j], acc[i][j], 0, 0, 0);
      }
    }
    #pragma unroll
    for (int i = 0; i < 4; i++){
      #pragma unroll
      for (int j = 0; j < 4; j++){
        #pragma unroll
        for (int r = 0; r < 4; r++){
          int grow = rb*64 + i*16 + l4*4 + r;
          int gcol = w*64 + j*16 + l15;
          float v = c1 * acc[i][j][r];
          if (E) v += c0 * E[(ll)grow*256 + gcol];
          C[(ll)grow*256 + gcol] = v;
        }
      }
    }
  }
}

__global__ __launch_bounds__(256)
void pinv_fused_k(const float* __restrict__ a2g, float* __restrict__ zAg, float* __restrict__ zBg,
                  float* __restrict__ t1g, float* __restrict__ t2g, float* __restrict__ t3g,
                  const unsigned* __restrict__ gm)
{
  __shared__ __align__(16) short As[64*64];
  __shared__ __align__(16) short Bs[256*64];
  int bh = blockIdx.x;
  const float* a2 = a2g + (ll)bh*65536;
  float* zA = zAg + (ll)bh*65536;
  float* zB = zBg + (ll)bh*65536;
  float* t1 = t1g + (ll)bh*65536;
  float* t2 = t2g + (ll)bh*65536;
  float* t3 = t3g + (ll)bh*65536;
  int tid = threadIdx.x;

  // z0 = a2^T / denom
  float inv = 1.f / (__uint_as_float(gm[0]) * __uint_as_float(gm[1]));
  for (int k = 0; k < 256; k++)
    zA[k*256 + tid] = a2[(ll)tid*256 + k] * inv;
  __syncthreads();

  float* zc = zA; float* zn = zB;
  for (int it = 0; it < 6; it++){
    bgemm256(a2, zc, t1, nullptr, 0.f, 1.f, As, Bs, tid);      // t1 = a2@z
    bgemm256(t1, t1, t2, t1, 7.f, -1.f, As, Bs, tid);          // t2 = 7t1 - t1@t1
    bgemm256(t1, t2, t3, t1, 15.f, -1.f, As, Bs, tid);         // t3 = 15t1 - t1@t2
    bgemm256(zc, t3, zn, zc, 3.25f, -0.25f, As, Bs, tid);      // zn = 3.25z - 0.25 z@t3
    float* tmp = zc; zc = zn; zn = tmp;
  }
  // result in zA after 6 iters
}

// ================= MFMA flash attention (attn1: full keys, normalized) =================
__global__ __launch_bounds__(256)
void mflash_k(const float* __restrict__ Q, const float* __restrict__ K,
              const float* __restrict__ V, float* __restrict__ O,
              int ldq, int ldk, int ldv, int ldo, int nkeys, float alpha,
              ll sQb, ll sQh, ll sKb, ll sKh, ll sVb, ll sVh, ll sOb, ll sOh)
{
  __shared__ __align__(16) short Qs[64*64];
  __shared__ __align__(16) short Ks[64*64];
  __shared__ __align__(16) short Vs[64*64];
  __shared__ __align__(16) short Ps[64*64];
  __shared__ float Sl[64][68];
  __shared__ float m_l[64], s_l[64], scl[64];
  int z = blockIdx.z; int b = z >> 3; int h = z & 7;
  Q += (ll)b*sQb + (ll)h*sQh;
  K += (ll)b*sKb + (ll)h*sKh;
  V += (ll)b*sVb + (ll)h*sVh;
  O += (ll)b*sOb + (ll)h*sOh;
  int m0 = blockIdx.x*64;
  int tid = threadIdx.x;
  int lane = tid & 63, w = tid >> 6;
  int l15 = lane & 15, l4 = lane >> 4;
  int wr = w >> 1, wc = w & 1;

  #pragma unroll
  for (int it = 0; it < 2; it++){
    int tau = tid + 256*it;
    int row = tau >> 3, slot = tau & 7;
    const float* qp = Q + (ll)(m0 + row)*ldq + slot*8;
    f32x4 p0 = *(const f32x4*)qp, p1 = *(const f32x4*)(qp+4);
    short8 v;
    v[0]=f2bf(p0[0]*alpha); v[1]=f2bf(p0[1]*alpha); v[2]=f2bf(p0[2]*alpha); v[3]=f2bf(p0[3]*alpha);
    v[4]=f2bf(p1[0]*alpha); v[5]=f2bf(p1[1]*alpha); v[6]=f2bf(p1[2]*alpha); v[7]=f2bf(p1[3]*alpha);
    ((short8*)Qs)[row*8 + (slot ^ (row&7))] = v;
  }
  if (tid < 64){ m_l[tid] = -1e30f; s_l[tid] = 0.f; }
  f32x4 o[2][2];
  #pragma unroll
  for (int i = 0; i < 2; i++)
    #pragma unroll
    for (int j = 0; j < 2; j++) o[i][j] = (f32x4){0.f,0.f,0.f,0.f};

  for (int n0 = 0; n0 < nkeys; n0 += 64){
    __syncthreads();
    #pragma unroll
    for (int it = 0; it < 2; it++){
      int tau = tid + 256*it;
      int row = tau >> 3, slot = tau & 7;
      const float* kp = K + (ll)(n0 + row)*ldk + slot*8;
      f32x4 p0 = *(const f32x4*)kp, p1 = *(const f32x4*)(kp+4);
      short8 v;
      v[0]=f2bf(p0[0]); v[1]=f2bf(p0[1]); v[2]=f2bf(p0[2]); v[3]=f2bf(p0[3]);
      v[4]=f2bf(p1[0]); v[5]=f2bf(p1[1]); v[6]=f2bf(p1[2]); v[7]=f2bf(p1[3]);
      ((short8*)Ks)[row*8 + (slot ^ (row&7))] = v;
    }
    #pragma unroll
    for (int it = 0; it < 2; it++){
      int key = (tid >> 3) + 32*it;
      int d0 = (tid & 7)*8;
      const float* vp = V + (ll)(n0 + key)*ldv + d0;
      f32x4 p0 = *(const f32x4*)vp, p1 = *(const f32x4*)(vp+4);
      #pragma unroll
      for (int j = 0; j < 8; j++){
        float val = (j < 4) ? p0[j] : p1[j-4];
        int d = d0 + j;
        Vs[d*64 + (((key>>3) ^ (d&7))<<3) + (key&7)] = f2bf(val);
      }
    }
    __syncthreads();
    // S = Q @ K^T
    f32x4 s[2][2];
    #pragma unroll
    for (int i = 0; i < 2; i++)
      #pragma unroll
      for (int j = 0; j < 2; j++) s[i][j] = (f32x4){0.f,0.f,0.f,0.f};
    #pragma unroll
    for (int kc = 0; kc < 2; kc++){
      short8 aq[2], bk[2];
      int g = kc*4 + l4;
      #pragma unroll
      for (int i = 0; i < 2; i++){
        int row = wr*32 + i*16 + l15;
        aq[i] = ((short8*)Qs)[row*8 + (g ^ (row&7))];
      }
      #pragma unroll
      for (int j = 0; j < 2; j++){
        int key = wc*32 + j*16 + l15;
        bk[j] = ((short8*)Ks)[key*8 + (g ^ (key&7))];
      }
      #pragma unroll
      for (int i = 0; i < 2; i++)
        #pragma unroll
        for (int j = 0; j < 2; j++)
          s[i][j] = __builtin_amdgcn_mfma_f32_16x16x32_bf16(aq[i], bk[j], s[i][j], 0, 0, 0);
    }
    #pragma unroll
    for (int i = 0; i < 2; i++)
      #pragma unroll
      for (int j = 0; j < 2; j++)
        #pragma unroll
        for (int r = 0; r < 4; r++)
          Sl[wr*32 + i*16 + l4*4 + r][wc*32 + j*16 + l15] = s[i][j][r];
    __syncthreads();
    // online softmax: 4 threads per row, 16 cols each
    {
      int row = tid >> 2, q = tid & 3, cb = q*16;
      float sv[16];
      float cmax = -1e30f;
      #pragma unroll
      for (int cc = 0; cc < 16; cc++){ sv[cc] = Sl[row][cb+cc]; cmax = fmaxf(cmax, sv[cc]); }
      cmax = fmaxf(cmax, __shfl_xor(cmax, 1));
      cmax = fmaxf(cmax, __shfl_xor(cmax, 2));
      float mprev = m_l[row];
      float newm = fmaxf(mprev, cmax);
      float lsum = 0.f;
      short8 pv0, pv1;
      #pragma unroll
      for (int cc = 0; cc < 8; cc++){ float e = expf(sv[cc]-newm); lsum += e; pv0[cc] = f2bf(e); }
      #pragma unroll
      for (int cc = 0; cc < 8; cc++){ float e = expf(sv[8+cc]-newm); lsum += e; pv1[cc] = f2bf(e); }
      lsum += __shfl_xor(lsum, 1);
      lsum += __shfl_xor(lsum, 2);
      ((short8*)Ps)[row*8 + ((2*q)   ^ (row&7))] = pv0;
      ((short8*)Ps)[row*8 + ((2*q+1) ^ (row&7))] = pv1;
      if (q == 0){
        float scale = expf(mprev - newm);
        m_l[row] = newm;
        s_l[row] = s_l[row]*scale + lsum;
        scl[row] = scale;
      }
    }
    __syncthreads();
    // rescale o, then PV
    #pragma unroll
    for (int i = 0; i < 2; i++)
      #pragma unroll
      for (int r = 0; r < 4; r++){
        float sc = scl[wr*32 + i*16 + l4*4 + r];
        #pragma unroll
        for (int j = 0; j < 2; j++) o[i][j][r] *= sc;
      }
    #pragma unroll
    for (int kc = 0; kc < 2; kc++){
      short8 ap[2], bv[2];
      int g = kc*4 + l4;
      #pragma unroll
      for (int i = 0; i < 2; i++){
        int row = wr*32 + i*16 + l15;
        ap[i] = ((short8*)Ps)[row*8 + (g ^ (row&7))];
      }
      #pragma unroll
      for (int j = 0; j < 2; j++){
        int d = wc*32 + j*16 + l15;
        bv[j] = ((short8*)Vs)[d*8 + (g ^ (d&7))];
      }
      #pragma unroll
      for (int i = 0; i < 2; i++)
        #pragma unroll
        for (int j = 0; j < 2; j++)
          o[i][j] = __builtin_amdgcn_mfma_f32_16x16x32_bf16(ap[i], bv[j], o[i][j], 0, 0, 0);
    }
  }
  #pragma unroll
  for (int i = 0; i < 2; i++)
    #pragma unroll
    for (int j = 0; j < 2; j++)
      #pragma unroll
      for (int r = 0; r < 4; r++){
        int row = wr*32 + i*16 + l4*4 + r;
        int col = wc*32 + j*16 + l15;
        O[(ll)(m0 + row)*ldo + col] = o[i][j][r] / s_l[row];
      }
}

// ======= MFMA flash attn3 partial (key-split, unnormalized output + stats) =======
__global__ __launch_bounds__(256)
void mflash3_part_k(const float* __restrict__ Q, const float* __restrict__ K,
                    const float* __restrict__ V,
                    float* __restrict__ po, float* __restrict__ pm, float* __restrict__ pl,
                    int ldq, int ldk, int ldv,
                    ll sQb, ll sQh, ll sKb, ll sKh, ll sVb, ll sVh)
{
  __shared__ __align__(16) short Qs[64*64];
  __shared__ __align__(16) short Ks[64*64];
  __shared__ __align__(16) short Vs[64*64];
  __shared__ __align__(16) short Ps[64*64];
  __shared__ float Sl[64][68];
  __shared__ float m_l[64], s_l[64], scl[64];
  int z = blockIdx.z; int b = z >> 3; int h = z & 7;
  int split = blockIdx.y;
  Q += (ll)b*sQb + (ll)h*sQh;
  K += (ll)b*sKb + (ll)h*sKh;
  V += (ll)b*sVb + (ll)h*sVh;
  int m0 = blockIdx.x*64;
  int koff = split * (NTOK/NSPLIT);
  int tid = threadIdx.x;
  int lane = tid & 63, w = tid >> 6;
  int l15 = lane & 15, l4 = lane >> 4;
  int wr = w >> 1, wc = w & 1;

  #pragma unroll
  for (int it = 0; it < 2; it++){
    int tau = tid + 256*it;
    int row = tau >> 3, slot = tau & 7;
    const float* qp = Q + (ll)(m0 + row)*ldq + slot*8;
    f32x4 p0 = *(const f32x4*)qp, p1 = *(const f32x4*)(qp+4);
    short8 v;
    v[0]=f2bf(p0[0]); v[1]=f2bf(p0[1]); v[2]=f2bf(p0[2]); v[3]=f2bf(p0[3]);
    v[4]=f2bf(p1[0]); v[5]=f2bf(p1[1]); v[6]=f2bf(p1[2]); v[7]=f2bf(p1[3]);
    ((short8*)Qs)[row*8 + (slot ^ (row&7))] = v;
  }
  if (tid < 64){ m_l[tid] = -1e30f; s_l[tid] = 0.f; }
  f32x4 o[2][2];
  #pragma unroll
  for (int i = 0; i < 2; i++)
    #pragma unroll
    for (int j = 0; j < 2; j++) o[i][j] = (f32x4){0.f,0.f,0.f,0.f};

  for (int n0 = koff; n0 < koff + NTOK/NSPLIT; n0 += 64){
    __syncthreads();
    #pragma unroll
    for (int it = 0; it < 2; it++){
      int tau = tid + 256*it;
      int row = tau >> 3, slot = tau & 7;
      const float* kp = K + (ll)(n0 + row)*ldk + slot*8;
      f32x4 p0 = *(const f32x4*)kp, p1 = *(const f32x4*)(kp+4);
      short8 v;
      v[0]=f2bf(p0[0]); v[1]=f2bf(p0[1]); v[2]=f2bf(p0[2]); v[3]=f2bf(p0[3]);
      v[4]=f2bf(p1[0]); v[5]=f2bf(p1[1]); v[6]=f2bf(p1[2]); v[7]=f2bf(p1[3]);
      ((short8*)Ks)[row*8 + (slot ^ (row&7))] = v;
    }
    #pragma unroll
    for (int it = 0; it < 2; it++){
      int key = (tid >> 3) + 32*it;
      int d0 = (tid & 7)*8;
      const float* vp = V + (ll)(n0 + key)*ldv + d0;
      f32x4 p0 = *(const f32x4*)vp, p1 = *(const f32x4*)(vp+4);
      #pragma unroll
      for (int j = 0; j < 8; j++){
        float val = (j < 4) ? p0[j] : p1[j-4];
        int d = d0 + j;
        Vs[d*64 + (((key>>3) ^ (d&7))<<3) + (key&7)] = f2bf(val);
      }
    }
    __syncthreads();
    f32x4 s[2][2];
    #pragma unroll
    for (int i = 0; i < 2; i++)
      #pragma unroll
      for (int j = 0; j < 2; j++) s[i][j] = (f32x4){0.f,0.f,0.f,0.f};
    #pragma unroll
    for (int kc = 0; kc < 2; kc++){
      short8 aq[2], bk[2];
      int g = kc*4 + l4;
      #pragma unroll
      for (int i = 0; i < 2; i++){
        int row = wr*32 + i*16 + l15;
        aq[i] = ((short8*)Qs)[row*8 + (g ^ (row&7))];
      }
      #pragma unroll
      for (int j = 0; j < 2; j++){
        int key = wc*32 + j*16 + l15;
        bk[j] = ((short8*)Ks)[key*8 + (g ^ (key&7))];
      }
      #pragma unroll
      for (int i = 0; i < 2; i++)
        #pragma unroll
        for (int j = 0; j < 2; j++)
          s[i][j] = __builtin_amdgcn_mfma_f32_16x16x32_bf16(aq[i], bk[j], s[i][j], 0, 0, 0);
    }
    #pragma unroll
    for (int i = 0; i < 2; i++)
      #pragma unroll
      for (int j = 0; j < 2; j++)
        #pragma unroll
        for (int r = 0; r < 4; r++)
          Sl[wr*32 + i*16 + l4*4 + r][wc*32 + j*16 + l15] = s[i][j][r];
    __syncthreads();
    {
      int row = tid >> 2, q = tid & 3, cb = q*16;
      float sv[16];
      float cmax = -1e30f;
      #pragma unroll
      for (int cc = 0; cc < 16; cc++){ sv[cc] = Sl[row][cb+cc]; cmax = fmaxf(cmax, sv[cc]); }
      cmax = fmaxf(cmax, __shfl_xor(cmax, 1));
      cmax = fmaxf(cmax, __shfl_xor(cmax, 2));
      float mprev = m_l[row];
      float newm = fmaxf(mprev, cmax);
      float lsum = 0.f;
      short8 pv0, pv1;
      #pragma unroll
      for (int cc = 0; cc < 8; cc++){ float e = expf(sv[cc]-newm); lsum += e; pv0[cc] = f2bf(e); }
      #pragma unroll
      for (int cc = 0; cc < 8; cc++){ float e = expf(sv[8+cc]-newm); lsum += e; pv1[cc] = f2bf(e); }
      lsum += __shfl_xor(lsum, 1);
      lsum += __shfl_xor(lsum, 2);
      ((short8*)Ps)[row*8 + ((2*q)   ^ (row&7))] = pv0;
      ((short8*)Ps)[row*8 + ((2*q+1) ^ (row&7))] = pv1;
      if (q == 0){
        float scale = expf(mprev - newm);
        m_l[row] = newm;
        s_l[row] = s_l[row]*scale + lsum;
        scl[row] = scale;
      }
    }
    __syncthreads();
    #pragma unroll
    for (int i = 0; i < 2; i++)
      #pragma unroll
      for (int r = 0; r < 4; r++){
        float sc = scl[wr*32 + i*16 + l4*4 + r];
        #pragma unroll
        for (int j = 0; j < 2; j++) o[i][j][r] *= sc;
      }
    #pragma unroll
    for (int kc = 0; kc < 2; kc++){
      short8 ap[2], bv[2];
      int g = kc*4 + l4;
      #pragma unroll
      for (int i = 0; i < 2; i++){
        int row = wr*32 + i*16 + l15;
        ap[i] = ((short8*)Ps)[row*8 + (g ^ (row&7))];
      }
      #pragma unroll
      for (int j = 0; j < 2; j++){
        int d = wc*32 + j*16 + l15;
        bv[j] = ((short8*)Vs)[d*8 + (g ^ (d&7))];
      }
      #pragma unroll
      for (int i = 0; i < 2; i++)
        #pragma unroll
        for (int j = 0; j < 2; j++)
          o[i][j] = __builtin_amdgcn_mfma_f32_16x16x32_bf16(ap[i], bv[j], o[i][j], 0, 0, 0);
    }
  }
  int bs = z*NSPLIT + split;
  #pragma unroll
  for (int i = 0; i < 2; i++)
    #pragma unroll
    for (int j = 0; j < 2; j++)
      #pragma unroll
      for (int r = 0; r < 4; r++){
        int row = wr*32 + i*16 + l4*4 + r;
        int col = wc*32 + j*16 + l15;
        po[((ll)bs*NLAND + m0 + row)*64 + col] = o[i][j][r];
      }
  if (tid < 64){
    pm[(ll)bs*NLAND + m0 + tid] = m_l[tid];
    pl[(ll)bs*NLAND + m0 + tid] = s_l[tid];
  }
}

// combine splits -> av[bh][row][64]
__global__ __launch_bounds__(256)
void flash3_comb_k(const float* __restrict__ po, const float* __restrict__ pm,
                   const float* __restrict__ pl, float* __restrict__ av){
  int bh = blockIdx.y;
  int row = blockIdx.x*4 + (threadIdx.x >> 6);
  int col = threadIdx.x & 63;
  float ms = -1e30f;
  float mv[NSPLIT];
  #pragma unroll
  for (int s = 0; s < NSPLIT; s++){
    mv[s] = pm[((ll)bh*NSPLIT + s)*NLAND + row];
    ms = fmaxf(ms, mv[s]);
  }
  float osum = 0.f, lsum = 0.f;
  #pragma unroll
  for (int s = 0; s < NSPLIT; s++){
    float wgt = expf(mv[s] - ms);
    osum += wgt * po[(((ll)bh*NSPLIT + s)*NLAND + row)*64 + col];
    lsum += wgt * pl[((ll)bh*NSPLIT + s)*NLAND + row];
  }
  av[((ll)bh*NLAND + row)*64 + col] = osum / lsum;
}

// ---------------- row softmax (a2) ----------------
__global__ __launch_bounds__(256) void softmax_rows_k(float* __restrict__ data, int cols){
  __shared__ float red[256];
  float* row = data + (ll)blockIdx.x * cols;
  int tid = threadIdx.x;
  float m = -1e30f;
  for (int c = tid; c < cols; c += 256) m = fmaxf(m, row[c]);
  m = bred(red, m, tid, 1);
  float s = 0.f;
  for (int c = tid; c < cols; c += 256){ float e = expf(row[c] - m); row[c] = e; s += e; }
  s = bred(red, s, tid, 0);
  float inv = 1.f/s;
  for (int c = tid; c < cols; c += 256) row[c] *= inv;
}

// ---------------- landmark means ----------------
__global__ __launch_bounds__(256) void landmarks_k(const float* __restrict__ qkv,
                                                   float* __restrict__ ql, float* __restrict__ kl){
  int idx = blockIdx.x*256 + threadIdx.x;
  int d = idx & 63;
  int i = (idx >> 6) & 255;
  int h = (idx >> 14) & 7;
  int b = idx >> 17;
  const float* base = qkv + ((ll)b*NTOK + (ll)i*16)*1536 + h*64 + d;
  float sq = 0.f, sk = 0.f;
  #pragma unroll
  for (int l = 0; l < 16; l++){ sq += base[l*1536]; sk += base[l*1536 + 512]; }
  ql[idx] = sq * (0.125f/16.f);
  kl[idx] = sk * (1.f/16.f);
}

// ---------------- pinv scaling ----------------
__global__ void init_scal_k(unsigned* s){ s[0] = 0u; s[1] = 0u; }

__global__ __launch_bounds__(256) void a2_maxsums_k(const float* __restrict__ a2, unsigned* __restrict__ gm){
  __shared__ float red[256];
  const float* A = a2 + (ll)blockIdx.x*65536;
  int tid = threadIdx.x;
  float cs = 0.f, rs = 0.f;
  for (int i = 0; i < 256; i++) cs += A[i*256 + tid];
  for (int j = 0; j < 256; j++) rs += A[tid*256 + j];
  float cmax = bred(red, cs, tid, 1);
  float rmax = bred(red, rs, tid, 1);
  if (tid == 0){
    atomicMax(gm + 0, __float_as_uint(rmax));
    atomicMax(gm + 1, __float_as_uint(cmax));
  }
}

// ---------------- depthwise conv ----------------
__global__ __launch_bounds__(256) void dwconv_add_k(const float* __restrict__ qkv,
                                                    const float* __restrict__ cw, float* __restrict__ out){
  __shared__ float sv[160][64];
  __shared__ float w[KCONV];
  int z = blockIdx.y; int b = z >> 3; int h = z & 7;
  int t0 = blockIdx.x * 128;
  int tid = threadIdx.x;
  if (tid < KCONV) w[tid] = cw[h*KCONV + tid];
  const float* vbase = qkv + (ll)b*NTOK*1536 + 1024 + h*64;
  for (int e = tid; e < 160*64; e += 256){
    int r = e >> 6, d = e & 63;
    int t = t0 - 16 + r;
    sv[r][d] = (t >= 0 && t < NTOK) ? vbase[(ll)t*1536 + d] : 0.f;
  }
  __syncthreads();
  float* obase = out + (ll)b*NTOK*512 + h*64;
  for (int e = tid; e < 128*64; e += 256){
    int r = e >> 6, d = e & 63;
    float s = 0.f;
    #pragma unroll
    for (int kk = 0; kk < KCONV; kk++) s += sv[r+kk][d]*w[kk];
    obase[(ll)(t0+r)*512 + d] += s;
  }
}

// ---------------- final head ----------------
__global__ __launch_bounds__(256) void head_k(const float* __restrict__ hb, const float* __restrict__ fns,
      const float* __restrict__ fnb, const float* __restrict__ fw, const float* __restrict__ fb,
      float* __restrict__ out){
  __shared__ float red[256];
  int b = blockIdx.x;
  const float* xr = hb + (ll)b*NTOK*DMODEL;
  int tid = threadIdx.x;
  float v0 = xr[tid], v1 = xr[tid+256];
  float mu = bred(red, v0+v1, tid, 0) * (1.f/512.f);
  float d0 = v0-mu, d1 = v1-mu;
  float var = bred(red, d0*d0 + d1*d1, tid, 0) * (1.f/512.f);
  float inv = 1.f/sqrtf(var + 1e-5f);
  float y0 = d0*inv*fns[tid]     + fnb[tid];
  float y1 = d1*inv*fns[tid+256] + fnb[tid+256];
  float dot = bred(red, y0*fw[tid] + y1*fw[tid+256], tid, 0);
  if (tid == 0){
    float logit = dot + fb[0];
    float prob = 1.f/(1.f + expf(-logit));
    out[b] = logit; out[4+b] = prob; out[8+b] = (prob > 0.5f) ? 1.f : 0.f;
  }
}

// =============================================================================
extern "C" void kernel_launch(void* const* d_in, const int* in_sizes, int n_in,
                              void* d_out, int out_size, void* d_ws, size_t ws_size,
                              hipStream_t stream)
{
  (void)in_sizes; (void)n_in; (void)out_size;
  const float* data  = (const float*)d_in[0];
  const float* fc1_w = (const float*)d_in[1];
  const float* fc1_b = (const float*)d_in[2];
  const float* cls   = (const float*)d_in[3];
  const float* ln_s  = (const float*)d_in[4];
  const float* ln_b  = (const float*)d_in[5];
  const float* qkv_w = (const float*)d_in[6];
  const float* out_w = (const float*)d_in[7];
  const float* out_b = (const float*)d_in[8];
  const float* convw = (const float*)d_in[9];
  const float* fns   = (const float*)d_in[10];
  const float* fnb   = (const float*)d_in[11];
  const float* fcw   = (const float*)d_in[12];
  const float* fcb   = (const float*)d_in[13];
  float* out = (float*)d_out;
  float* ws  = (float*)d_ws;

  float* h   = ws;                   //  8,388,608
  float* x   = h   + 8388608;        //  8,388,608
  float* qkv = x   + 8388608;        // 25,165,824
  float* ql  = qkv + 25165824;       //    524,288
  float* kl  = ql  + 524288;         //    524,288
  float* a2  = kl  + 524288;         //  2,097,152
  float* zA  = a2  + 2097152;        //  2,097,152
  float* zB  = zA  + 2097152;        //  2,097,152
  float* t1  = zB  + 2097152;        //  2,097,152
  float* t2  = t1  + 2097152;        //  2,097,152
  float* t3  = t2  + 2097152;        //  2,097,152
  float* av  = t3  + 2097152;        //    524,288
  float* y2  = av  + 524288;         //    524,288
  unsigned* scal = (unsigned*)(y2 + 524288);
  float* pe = t1;                    // alias (dead before pinv)
  float* po = t1;                    // alias: spans t1+t2 (dead after pinv)
  float* pm = t3;                    // alias
  float* pl = t3 + 65536;            // alias

  const size_t NEED = (size_t)(56623104 + 16) * sizeof(float);
  if (ws_size < NEED) return;

  pe_table_k<<<(TSEQ*DMODEL + 255)/256, 256, 0, stream>>>(pe);
  mgemm<128,128><<<dim3(4, 128, 1), 256, 0, stream>>>(
      data, fc1_w, h, nullptr, fc1_b,
      NBATCH*TSEQ, INDIM, INDIM, DMODEL, DMODEL,
      0, 0, 0, 0.f, 0.f, 1|2|16);
  pe_cls_add_k<<<(NBATCH*NTOK*DMODEL)/256, 256, 0, stream>>>(h, cls, pe);

  for (int L = 0; L < 2; L++){
    const float* qw = qkv_w + (ll)L*DMODEL*1536;
    const float* ow = out_w + (ll)L*DMODEL*DMODEL;
    const float* ob = out_b + (ll)L*DMODEL;
    const float* cw = convw + (ll)L*NHEAD*KCONV;

    ln_rows_k<<<NBATCH*NTOK, 256, 0, stream>>>(h, x, ln_s + L*DMODEL, ln_b + L*DMODEL);
    mgemm<128,128><<<dim3(12, 128, 1), 256, 0, stream>>>(
        x, qw, qkv, nullptr, nullptr,
        NBATCH*NTOK, DMODEL, DMODEL, 1536, 1536,
        0, 0, 0, 0.f, 0.f, 0);
    landmarks_k<<<2048, 256, 0, stream>>>(qkv, ql, kl);

    // attn2 = softmax(ql @ kl^T)  (fp32, feeds pinv scaling)
    gemm_nt<<<dim3(4, 4, NBH), 256, 0, stream>>>(
        ql, kl, a2, 64, 64, 256,
        131072, 16384, 131072, 16384, 524288, 65536, 1.f);
    softmax_rows_k<<<NBH*NLAND, 256, 0, stream>>>(a2, 256);

    init_scal_k<<<1, 1, 0, stream>>>(scal);
    a2_maxsums_k<<<NBH, 256, 0, stream>>>(a2, scal);

    // fused Newton-Schulz (zinit + 6 iters, all in-kernel); result in zA
    pinv_fused_k<<<32, 256, 0, stream>>>(a2, zA, zB, t1, t2, t3, scal);

    // av = softmax(ql @ k^T) @ v  -- MFMA key-split flash + combine
    mflash3_part_k<<<dim3(4, NSPLIT, NBH), 256, 0, stream>>>(
        ql, qkv + 512, qkv + 1024, po, pm, pl,
        64, 1536, 1536,
        131072, 16384, (ll)NTOK*1536, 64, (ll)NTOK*1536, 64);
    flash3_comb_k<<<dim3(64, NBH), 256, 0, stream>>>(po, pm, pl, av);

    // y2 = pinv @ av
    mgemm<64,64><<<dim3(1, 4, NBH), 256, 0, stream>>>(
        zA, av, y2, nullptr, nullptr, 256, 256, 256, 64, 64,
        65536, 16384, 16384, 0.f, 0.f, 0);

    // x = softmax(0.125 q @ kl^T) @ y2  (MFMA flash)
    mflash_k<<<dim3(64, 1, NBH), 256, 0, stream>>>(
        qkv, kl, y2, x,
        1536, 64, 64, 512, NLAND, 0.125f,
        (ll)NTOK*1536, 64, 131072, 16384, 131072, 16384, (ll)NTOK*512, 64);

    // x += depthwise_conv(v)
    dwconv_add_k<<<dim3(32, NBH), 256, 0, stream>>>(qkv, cw, x);

    // h = h + x @ out_w + out_b
    mgemm<128,128><<<dim3(4, 128, 1), 256, 0, stream>>>(
        x, ow, h, nullptr, ob,
        NBATCH*NTOK, DMODEL, DMODEL, DMODEL, DMODEL,
        0, 0, 0, 0.f, 0.f, 1|8);
  }

  head_k<<<4, 256, 0, stream>>>(h, fns, fnb, fcw, fcb, out);
}

// Round 5
// 1628.502 us; speedup vs baseline: 2.8251x; 2.8251x over previous
//
#include <hip/hip_runtime.h>
#include <math.h>

typedef long long ll;
typedef __attribute__((ext_vector_type(8))) short short8;
typedef __attribute__((ext_vector_type(4))) float f32x4;

#define NBATCH 4
#define TSEQ   4095
#define NTOK   4096
#define DMODEL 512
#define NHEAD  8
#define DHEAD  64
#define NLAND  256
#define INDIM  1024
#define KCONV  33
#define NBH    32
#define NSPLIT 8

// ---------------- helpers ----------------
__device__ __forceinline__ float bred(float* red, float v, int tid, int op){
  red[tid] = v; __syncthreads();
  for (int s = 128; s > 0; s >>= 1){
    if (tid < s) red[tid] = op ? fmaxf(red[tid], red[tid+s]) : (red[tid] + red[tid+s]);
    __syncthreads();
  }
  float r = red[0];
  __syncthreads();
  return r;
}

__device__ __forceinline__ short f2bf(float f){  // RNE f32->bf16
  unsigned u = __float_as_uint(f);
  u += 0x7fff + ((u>>16)&1);
  return (short)(u>>16);
}

// ---------------- PE table ----------------
__global__ __launch_bounds__(256) void pe_table_k(float* __restrict__ pe){
  int idx = blockIdx.x*256 + threadIdx.x;
  if (idx >= TSEQ*DMODEL) return;
  int c = idx & 511; int t = idx >> 9;
  const double NEG = -9.210340371976184 / 512.0;
  double div = exp((double)(c & ~1) * NEG);
  double ang = (double)t * div;
  pe[idx] = (c & 1) ? (float)cos(ang) : (float)sin(ang);
}

__global__ __launch_bounds__(256) void pe_cls_add_k(float* __restrict__ hb, const float* __restrict__ cls,
                                                    const float* __restrict__ pe){
  ll idx = (ll)blockIdx.x*256 + threadIdx.x;
  int c = (int)(idx & 511);
  ll rn = idx >> 9;
  int n = (int)(rn & 4095);
  if (n == 0) hb[idx] = cls[c];
  else        hb[idx] += pe[(ll)(n-1)*512 + c];
}

// ---------------- LayerNorm rows (D=512) ----------------
__global__ __launch_bounds__(256) void ln_rows_k(const float* __restrict__ in, float* __restrict__ out,
                                                 const float* __restrict__ sc, const float* __restrict__ bi){
  __shared__ float red[256];
  ll row = blockIdx.x;
  const float* xr = in + row*DMODEL;
  float* orow = out + row*DMODEL;
  int tid = threadIdx.x;
  float v0 = xr[tid], v1 = xr[tid+256];
  float mu = bred(red, v0+v1, tid, 0) * (1.f/512.f);
  float d0 = v0-mu, d1 = v1-mu;
  float var = bred(red, d0*d0 + d1*d1, tid, 0) * (1.f/512.f);
  float inv = 1.f / sqrtf(var + 1e-5f);
  orow[tid]     = d0*inv*sc[tid]     + bi[tid];
  orow[tid+256] = d1*inv*sc[tid+256] + bi[tid+256];
}

// ============ bf16 MFMA GEMM (dense layers, pinv stages, y2) ============
// flags: 1=+bias[n]  2=relu  4=C=c0*E+c1*acc  8=+=C residual  16=fc1 row remap
template<int BM, int BN>
__global__ __launch_bounds__(256)
void mgemm(const float* __restrict__ A, const float* __restrict__ Bm,
           float* __restrict__ C, const float* __restrict__ E,
           const float* __restrict__ bias,
           int Mr, int K, int lda, int ldb, int ldc,
           ll sA, ll sB, ll sC,
           float c0, float c1, int flags)
{
  constexpr int MI = BM/32, NJ = BN/32;
  __shared__ __align__(16) short As[BM*64];
  __shared__ __align__(16) short Bs[BN*64];
  int z = blockIdx.z;
  A += (ll)z*sA; Bm += (ll)z*sB; C += (ll)z*sC;
  if (E) E += (ll)z*sC;
  int n0 = blockIdx.x*BN, m0 = blockIdx.y*BM;
  int tid = threadIdx.x;
  int lane = tid & 63, w = tid >> 6;
  int wr = w >> 1, wc = w & 1;
  int l15 = lane & 15, l4 = lane >> 4;

  f32x4 acc[MI][NJ];
  #pragma unroll
  for (int i = 0; i < MI; i++)
    #pragma unroll
    for (int j = 0; j < NJ; j++) acc[i][j] = (f32x4){0.f,0.f,0.f,0.f};

  for (int k0 = 0; k0 < K; k0 += 64){
    #pragma unroll
    for (int it = 0; it < BM/32; ++it){
      int tau = tid + 256*it;
      int row = tau >> 3, slot = tau & 7;
      int grow = m0 + row;
      f32x4 p0 = {0.f,0.f,0.f,0.f}, p1 = {0.f,0.f,0.f,0.f};
      if (grow < Mr){
        const float* ap = A + (ll)grow*lda + k0 + slot*8;
        p0 = *(const f32x4*)ap; p1 = *(const f32x4*)(ap+4);
      }
      short8 v;
      v[0]=f2bf(p0[0]); v[1]=f2bf(p0[1]); v[2]=f2bf(p0[2]); v[3]=f2bf(p0[3]);
      v[4]=f2bf(p1[0]); v[5]=f2bf(p1[1]); v[6]=f2bf(p1[2]); v[7]=f2bf(p1[3]);
      ((short8*)As)[row*8 + (slot ^ (row&7))] = v;
    }
    #pragma unroll
    for (int it = 0; it < BN/32; ++it){
      int tau = tid + 256*it;
      int n = tau & (BN-1), slot = tau >> (BN==128 ? 7 : 6);
      const float* bp = Bm + (ll)(k0 + slot*8)*ldb + n0 + n;
      short8 v;
      #pragma unroll
      for (int i = 0; i < 8; i++) v[i] = f2bf(bp[(ll)i*ldb]);
      ((short8*)Bs)[n*8 + (slot ^ (n&7))] = v;
    }
    __syncthreads();
    #pragma unroll
    for (int kc = 0; kc < 2; kc++){
      short8 af[MI], bf[NJ];
      #pragma unroll
      for (int i = 0; i < MI; i++){
        int row = wr*(BM/2) + i*16 + l15;
        int g = kc*4 + l4;
        af[i] = ((short8*)As)[row*8 + (g ^ (row&7))];
      }
      #pragma unroll
      for (int j = 0; j < NJ; j++){
        int col = wc*(BN/2) + j*16 + l15;
        int g = kc*4 + l4;
        bf[j] = ((short8*)Bs)[col*8 + (g ^ (col&7))];
      }
      #pragma unroll
      for (int i = 0; i < MI; i++)
        #pragma unroll
        for (int j = 0; j < NJ; j++)
          acc[i][j] = __builtin_amdgcn_mfma_f32_16x16x32_bf16(af[i], bf[j], acc[i][j], 0, 0, 0);
    }
    __syncthreads();
  }

  #pragma unroll
  for (int i = 0; i < MI; i++){
    int rbase = m0 + wr*(BM/2) + i*16 + l4*4;
    #pragma unroll
    for (int j = 0; j < NJ; j++){
      int col = n0 + wc*(BN/2) + j*16 + l15;
      #pragma unroll
      for (int r = 0; r < 4; r++){
        int m = rbase + r;
        if (m >= Mr) continue;
        float v = acc[i][j][r];
        if (flags & 4) v = c0 * E[(ll)m*ldc + col] + c1 * v;
        if (flags & 1) v += bias[col];
        if (flags & 2) v = fmaxf(v, 0.f);
        int om = (flags & 16) ? (m + m/TSEQ + 1) : m;
        ll ci = (ll)om*ldc + col;
        if (flags & 8) v += C[ci];
        C[ci] = v;
      }
    }
  }
}

// ---------------- NT GEMM fp32 (attn2 scores only) ----------------
__global__ __launch_bounds__(256)
void gemm_nt(const float* __restrict__ A, const float* __restrict__ Bm, float* __restrict__ C,
             int lda, int ldb, int ldc,
             ll sAb, ll sAh, ll sBb, ll sBh, ll sCb, ll sCh,
             float alpha)
{
  __shared__ float As[64][65];
  __shared__ float Bs[64][65];
  int z = blockIdx.z; int b = z >> 3; int h = z & 7;
  A  += (ll)b*sAb + (ll)h*sAh;
  Bm += (ll)b*sBb + (ll)h*sBh;
  C  += (ll)b*sCb + (ll)h*sCh;
  int n0 = blockIdx.x*64, m0 = blockIdx.y*64;
  int tid = threadIdx.x;
  int kk = tid & 63, rr = tid >> 6;
  #pragma unroll
  for (int r = 0; r < 16; r++){
    As[rr + 4*r][kk] = A [(ll)(m0 + rr + 4*r)*lda + kk];
    Bs[rr + 4*r][kk] = Bm[(ll)(n0 + rr + 4*r)*ldb + kk];
  }
  __syncthreads();
  int tx = tid & 15, ty = tid >> 4;
  float acc[4][4] = {};
  for (int k = 0; k < 64; k++){
    float a[4], bv[4];
    #pragma unroll
    for (int i = 0; i < 4; i++) a[i] = As[ty + 16*i][k];
    #pragma unroll
    for (int j = 0; j < 4; j++) bv[j] = Bs[tx + 16*j][k];
    #pragma unroll
    for (int i = 0; i < 4; i++)
      #pragma unroll
      for (int j = 0; j < 4; j++)
        acc[i][j] += a[i]*bv[j];
  }
  #pragma unroll
  for (int i = 0; i < 4; i++)
    #pragma unroll
    for (int j = 0; j < 4; j++)
      C[(ll)(m0 + ty + 16*i)*ldc + n0 + tx + 16*j] = alpha * acc[i][j];
}

// ================= MFMA flash attention (attn1: full keys, normalized) =================
__global__ __launch_bounds__(256)
void mflash_k(const float* __restrict__ Q, const float* __restrict__ K,
              const float* __restrict__ V, float* __restrict__ O,
              int ldq, int ldk, int ldv, int ldo, int nkeys, float alpha,
              ll sQb, ll sQh, ll sKb, ll sKh, ll sVb, ll sVh, ll sOb, ll sOh)
{
  __shared__ __align__(16) short Qs[64*64];
  __shared__ __align__(16) short Ks[64*64];
  __shared__ __align__(16) short Vs[64*64];
  __shared__ __align__(16) short Ps[64*64];
  __shared__ float Sl[64][68];
  __shared__ float m_l[64], s_l[64], scl[64];
  int z = blockIdx.z; int b = z >> 3; int h = z & 7;
  Q += (ll)b*sQb + (ll)h*sQh;
  K += (ll)b*sKb + (ll)h*sKh;
  V += (ll)b*sVb + (ll)h*sVh;
  O += (ll)b*sOb + (ll)h*sOh;
  int m0 = blockIdx.x*64;
  int tid = threadIdx.x;
  int lane = tid & 63, w = tid >> 6;
  int l15 = lane & 15, l4 = lane >> 4;
  int wr = w >> 1, wc = w & 1;

  #pragma unroll
  for (int it = 0; it < 2; it++){
    int tau = tid + 256*it;
    int row = tau >> 3, slot = tau & 7;
    const float* qp = Q + (ll)(m0 + row)*ldq + slot*8;
    f32x4 p0 = *(const f32x4*)qp, p1 = *(const f32x4*)(qp+4);
    short8 v;
    v[0]=f2bf(p0[0]*alpha); v[1]=f2bf(p0[1]*alpha); v[2]=f2bf(p0[2]*alpha); v[3]=f2bf(p0[3]*alpha);
    v[4]=f2bf(p1[0]*alpha); v[5]=f2bf(p1[1]*alpha); v[6]=f2bf(p1[2]*alpha); v[7]=f2bf(p1[3]*alpha);
    ((short8*)Qs)[row*8 + (slot ^ (row&7))] = v;
  }
  if (tid < 64){ m_l[tid] = -1e30f; s_l[tid] = 0.f; }
  f32x4 o[2][2];
  #pragma unroll
  for (int i = 0; i < 2; i++)
    #pragma unroll
    for (int j = 0; j < 2; j++) o[i][j] = (f32x4){0.f,0.f,0.f,0.f};

  for (int n0 = 0; n0 < nkeys; n0 += 64){
    __syncthreads();
    #pragma unroll
    for (int it = 0; it < 2; it++){
      int tau = tid + 256*it;
      int row = tau >> 3, slot = tau & 7;
      const float* kp = K + (ll)(n0 + row)*ldk + slot*8;
      f32x4 p0 = *(const f32x4*)kp, p1 = *(const f32x4*)(kp+4);
      short8 v;
      v[0]=f2bf(p0[0]); v[1]=f2bf(p0[1]); v[2]=f2bf(p0[2]); v[3]=f2bf(p0[3]);
      v[4]=f2bf(p1[0]); v[5]=f2bf(p1[1]); v[6]=f2bf(p1[2]); v[7]=f2bf(p1[3]);
      ((short8*)Ks)[row*8 + (slot ^ (row&7))] = v;
    }
    #pragma unroll
    for (int it = 0; it < 2; it++){
      int key = (tid >> 3) + 32*it;
      int d0 = (tid & 7)*8;
      const float* vp = V + (ll)(n0 + key)*ldv + d0;
      f32x4 p0 = *(const f32x4*)vp, p1 = *(const f32x4*)(vp+4);
      #pragma unroll
      for (int j = 0; j < 8; j++){
        float val = (j < 4) ? p0[j] : p1[j-4];
        int d = d0 + j;
        Vs[d*64 + (((key>>3) ^ (d&7))<<3) + (key&7)] = f2bf(val);
      }
    }
    __syncthreads();
    // S = Q @ K^T
    f32x4 s[2][2];
    #pragma unroll
    for (int i = 0; i < 2; i++)
      #pragma unroll
      for (int j = 0; j < 2; j++) s[i][j] = (f32x4){0.f,0.f,0.f,0.f};
    #pragma unroll
    for (int kc = 0; kc < 2; kc++){
      short8 aq[2], bk[2];
      int g = kc*4 + l4;
      #pragma unroll
      for (int i = 0; i < 2; i++){
        int row = wr*32 + i*16 + l15;
        aq[i] = ((short8*)Qs)[row*8 + (g ^ (row&7))];
      }
      #pragma unroll
      for (int j = 0; j < 2; j++){
        int key = wc*32 + j*16 + l15;
        bk[j] = ((short8*)Ks)[key*8 + (g ^ (key&7))];
      }
      #pragma unroll
      for (int i = 0; i < 2; i++)
        #pragma unroll
        for (int j = 0; j < 2; j++)
          s[i][j] = __builtin_amdgcn_mfma_f32_16x16x32_bf16(aq[i], bk[j], s[i][j], 0, 0, 0);
    }
    #pragma unroll
    for (int i = 0; i < 2; i++)
      #pragma unroll
      for (int j = 0; j < 2; j++)
        #pragma unroll
        for (int r = 0; r < 4; r++)
          Sl[wr*32 + i*16 + l4*4 + r][wc*32 + j*16 + l15] = s[i][j][r];
    __syncthreads();
    // online softmax: 4 threads per row, 16 cols each
    {
      int row = tid >> 2, q = tid & 3, cb = q*16;
      float sv[16];
      float cmax = -1e30f;
      #pragma unroll
      for (int cc = 0; cc < 16; cc++){ sv[cc] = Sl[row][cb+cc]; cmax = fmaxf(cmax, sv[cc]); }
      cmax = fmaxf(cmax, __shfl_xor(cmax, 1));
      cmax = fmaxf(cmax, __shfl_xor(cmax, 2));
      float mprev = m_l[row];
      float newm = fmaxf(mprev, cmax);
      float lsum = 0.f;
      short8 pv0, pv1;
      #pragma unroll
      for (int cc = 0; cc < 8; cc++){ float e = expf(sv[cc]-newm); lsum += e; pv0[cc] = f2bf(e); }
      #pragma unroll
      for (int cc = 0; cc < 8; cc++){ float e = expf(sv[8+cc]-newm); lsum += e; pv1[cc] = f2bf(e); }
      lsum += __shfl_xor(lsum, 1);
      lsum += __shfl_xor(lsum, 2);
      ((short8*)Ps)[row*8 + ((2*q)   ^ (row&7))] = pv0;
      ((short8*)Ps)[row*8 + ((2*q+1) ^ (row&7))] = pv1;
      if (q == 0){
        float scale = expf(mprev - newm);
        m_l[row] = newm;
        s_l[row] = s_l[row]*scale + lsum;
        scl[row] = scale;
      }
    }
    __syncthreads();
    // rescale o, then PV
    #pragma unroll
    for (int i = 0; i < 2; i++)
      #pragma unroll
      for (int r = 0; r < 4; r++){
        float sc = scl[wr*32 + i*16 + l4*4 + r];
        #pragma unroll
        for (int j = 0; j < 2; j++) o[i][j][r] *= sc;
      }
    #pragma unroll
    for (int kc = 0; kc < 2; kc++){
      short8 ap[2], bv[2];
      int g = kc*4 + l4;
      #pragma unroll
      for (int i = 0; i < 2; i++){
        int row = wr*32 + i*16 + l15;
        ap[i] = ((short8*)Ps)[row*8 + (g ^ (row&7))];
      }
      #pragma unroll
      for (int j = 0; j < 2; j++){
        int d = wc*32 + j*16 + l15;
        bv[j] = ((short8*)Vs)[d*8 + (g ^ (d&7))];
      }
      #pragma unroll
      for (int i = 0; i < 2; i++)
        #pragma unroll
        for (int j = 0; j < 2; j++)
          o[i][j] = __builtin_amdgcn_mfma_f32_16x16x32_bf16(ap[i], bv[j], o[i][j], 0, 0, 0);
    }
  }
  #pragma unroll
  for (int i = 0; i < 2; i++)
    #pragma unroll
    for (int j = 0; j < 2; j++)
      #pragma unroll
      for (int r = 0; r < 4; r++){
        int row = wr*32 + i*16 + l4*4 + r;
        int col = wc*32 + j*16 + l15;
        O[(ll)(m0 + row)*ldo + col] = o[i][j][r] / s_l[row];
      }
}

// ======= MFMA flash attn3 partial (key-split, unnormalized output + stats) =======
__global__ __launch_bounds__(256)
void mflash3_part_k(const float* __restrict__ Q, const float* __restrict__ K,
                    const float* __restrict__ V,
                    float* __restrict__ po, float* __restrict__ pm, float* __restrict__ pl,
                    int ldq, int ldk, int ldv,
                    ll sQb, ll sQh, ll sKb, ll sKh, ll sVb, ll sVh)
{
  __shared__ __align__(16) short Qs[64*64];
  __shared__ __align__(16) short Ks[64*64];
  __shared__ __align__(16) short Vs[64*64];
  __shared__ __align__(16) short Ps[64*64];
  __shared__ float Sl[64][68];
  __shared__ float m_l[64], s_l[64], scl[64];
  int z = blockIdx.z; int b = z >> 3; int h = z & 7;
  int split = blockIdx.y;
  Q += (ll)b*sQb + (ll)h*sQh;
  K += (ll)b*sKb + (ll)h*sKh;
  V += (ll)b*sVb + (ll)h*sVh;
  int m0 = blockIdx.x*64;
  int koff = split * (NTOK/NSPLIT);
  int tid = threadIdx.x;
  int lane = tid & 63, w = tid >> 6;
  int l15 = lane & 15, l4 = lane >> 4;
  int wr = w >> 1, wc = w & 1;

  #pragma unroll
  for (int it = 0; it < 2; it++){
    int tau = tid + 256*it;
    int row = tau >> 3, slot = tau & 7;
    const float* qp = Q + (ll)(m0 + row)*ldq + slot*8;
    f32x4 p0 = *(const f32x4*)qp, p1 = *(const f32x4*)(qp+4);
    short8 v;
    v[0]=f2bf(p0[0]); v[1]=f2bf(p0[1]); v[2]=f2bf(p0[2]); v[3]=f2bf(p0[3]);
    v[4]=f2bf(p1[0]); v[5]=f2bf(p1[1]); v[6]=f2bf(p1[2]); v[7]=f2bf(p1[3]);
    ((short8*)Qs)[row*8 + (slot ^ (row&7))] = v;
  }
  if (tid < 64){ m_l[tid] = -1e30f; s_l[tid] = 0.f; }
  f32x4 o[2][2];
  #pragma unroll
  for (int i = 0; i < 2; i++)
    #pragma unroll
    for (int j = 0; j < 2; j++) o[i][j] = (f32x4){0.f,0.f,0.f,0.f};

  for (int n0 = koff; n0 < koff + NTOK/NSPLIT; n0 += 64){
    __syncthreads();
    #pragma unroll
    for (int it = 0; it < 2; it++){
      int tau = tid + 256*it;
      int row = tau >> 3, slot = tau & 7;
      const float* kp = K + (ll)(n0 + row)*ldk + slot*8;
      f32x4 p0 = *(const f32x4*)kp, p1 = *(const f32x4*)(kp+4);
      short8 v;
      v[0]=f2bf(p0[0]); v[1]=f2bf(p0[1]); v[2]=f2bf(p0[2]); v[3]=f2bf(p0[3]);
      v[4]=f2bf(p1[0]); v[5]=f2bf(p1[1]); v[6]=f2bf(p1[2]); v[7]=f2bf(p1[3]);
      ((short8*)Ks)[row*8 + (slot ^ (row&7))] = v;
    }
    #pragma unroll
    for (int it = 0; it < 2; it++){
      int key = (tid >> 3) + 32*it;
      int d0 = (tid & 7)*8;
      const float* vp = V + (ll)(n0 + key)*ldv + d0;
      f32x4 p0 = *(const f32x4*)vp, p1 = *(const f32x4*)(vp+4);
      #pragma unroll
      for (int j = 0; j < 8; j++){
        float val = (j < 4) ? p0[j] : p1[j-4];
        int d = d0 + j;
        Vs[d*64 + (((key>>3) ^ (d&7))<<3) + (key&7)] = f2bf(val);
      }
    }
    __syncthreads();
    f32x4 s[2][2];
    #pragma unroll
    for (int i = 0; i < 2; i++)
      #pragma unroll
      for (int j = 0; j < 2; j++) s[i][j] = (f32x4){0.f,0.f,0.f,0.f};
    #pragma unroll
    for (int kc = 0; kc < 2; kc++){
      short8 aq[2], bk[2];
      int g = kc*4 + l4;
      #pragma unroll
      for (int i = 0; i < 2; i++){
        int row = wr*32 + i*16 + l15;
        aq[i] = ((short8*)Qs)[row*8 + (g ^ (row&7))];
      }
      #pragma unroll
      for (int j = 0; j < 2; j++){
        int key = wc*32 + j*16 + l15;
        bk[j] = ((short8*)Ks)[key*8 + (g ^ (key&7))];
      }
      #pragma unroll
      for (int i = 0; i < 2; i++)
        #pragma unroll
        for (int j = 0; j < 2; j++)
          s[i][j] = __builtin_amdgcn_mfma_f32_16x16x32_bf16(aq[i], bk[j], s[i][j], 0, 0, 0);
    }
    #pragma unroll
    for (int i = 0; i < 2; i++)
      #pragma unroll
      for (int j = 0; j < 2; j++)
        #pragma unroll
        for (int r = 0; r < 4; r++)
          Sl[wr*32 + i*16 + l4*4 + r][wc*32 + j*16 + l15] = s[i][j][r];
    __syncthreads();
    {
      int row = tid >> 2, q = tid & 3, cb = q*16;
      float sv[16];
      float cmax = -1e30f;
      #pragma unroll
      for (int cc = 0; cc < 16; cc++){ sv[cc] = Sl[row][cb+cc]; cmax = fmaxf(cmax, sv[cc]); }
      cmax = fmaxf(cmax, __shfl_xor(cmax, 1));
      cmax = fmaxf(cmax, __shfl_xor(cmax, 2));
      float mprev = m_l[row];
      float newm = fmaxf(mprev, cmax);
      float lsum = 0.f;
      short8 pv0, pv1;
      #pragma unroll
      for (int cc = 0; cc < 8; cc++){ float e = expf(sv[cc]-newm); lsum += e; pv0[cc] = f2bf(e); }
      #pragma unroll
      for (int cc = 0; cc < 8; cc++){ float e = expf(sv[8+cc]-newm); lsum += e; pv1[cc] = f2bf(e); }
      lsum += __shfl_xor(lsum, 1);
      lsum += __shfl_xor(lsum, 2);
      ((short8*)Ps)[row*8 + ((2*q)   ^ (row&7))] = pv0;
      ((short8*)Ps)[row*8 + ((2*q+1) ^ (row&7))] = pv1;
      if (q == 0){
        float scale = expf(mprev - newm);
        m_l[row] = newm;
        s_l[row] = s_l[row]*scale + lsum;
        scl[row] = scale;
      }
    }
    __syncthreads();
    #pragma unroll
    for (int i = 0; i < 2; i++)
      #pragma unroll
      for (int r = 0; r < 4; r++){
        float sc = scl[wr*32 + i*16 + l4*4 + r];
        #pragma unroll
        for (int j = 0; j < 2; j++) o[i][j][r] *= sc;
      }
    #pragma unroll
    for (int kc = 0; kc < 2; kc++){
      short8 ap[2], bv[2];
      int g = kc*4 + l4;
      #pragma unroll
      for (int i = 0; i < 2; i++){
        int row = wr*32 + i*16 + l15;
        ap[i] = ((short8*)Ps)[row*8 + (g ^ (row&7))];
      }
      #pragma unroll
      for (int j = 0; j < 2; j++){
        int d = wc*32 + j*16 + l15;
        bv[j] = ((short8*)Vs)[d*8 + (g ^ (d&7))];
      }
      #pragma unroll
      for (int i = 0; i < 2; i++)
        #pragma unroll
        for (int j = 0; j < 2; j++)
          o[i][j] = __builtin_amdgcn_mfma_f32_16x16x32_bf16(ap[i], bv[j], o[i][j], 0, 0, 0);
    }
  }
  int bs = z*NSPLIT + split;
  #pragma unroll
  for (int i = 0; i < 2; i++)
    #pragma unroll
    for (int j = 0; j < 2; j++)
      #pragma unroll
      for (int r = 0; r < 4; r++){
        int row = wr*32 + i*16 + l4*4 + r;
        int col = wc*32 + j*16 + l15;
        po[((ll)bs*NLAND + m0 + row)*64 + col] = o[i][j][r];
      }
  if (tid < 64){
    pm[(ll)bs*NLAND + m0 + tid] = m_l[tid];
    pl[(ll)bs*NLAND + m0 + tid] = s_l[tid];
  }
}

// combine splits -> av[bh][row][64]
__global__ __launch_bounds__(256)
void flash3_comb_k(const float* __restrict__ po, const float* __restrict__ pm,
                   const float* __restrict__ pl, float* __restrict__ av){
  int bh = blockIdx.y;
  int row = blockIdx.x*4 + (threadIdx.x >> 6);
  int col = threadIdx.x & 63;
  float ms = -1e30f;
  float mv[NSPLIT];
  #pragma unroll
  for (int s = 0; s < NSPLIT; s++){
    mv[s] = pm[((ll)bh*NSPLIT + s)*NLAND + row];
    ms = fmaxf(ms, mv[s]);
  }
  float osum = 0.f, lsum = 0.f;
  #pragma unroll
  for (int s = 0; s < NSPLIT; s++){
    float wgt = expf(mv[s] - ms);
    osum += wgt * po[(((ll)bh*NSPLIT + s)*NLAND + row)*64 + col];
    lsum += wgt * pl[((ll)bh*NSPLIT + s)*NLAND + row];
  }
  av[((ll)bh*NLAND + row)*64 + col] = osum / lsum;
}

// ---------------- row softmax (a2) ----------------
__global__ __launch_bounds__(256) void softmax_rows_k(float* __restrict__ data, int cols){
  __shared__ float red[256];
  float* row = data + (ll)blockIdx.x * cols;
  int tid = threadIdx.x;
  float m = -1e30f;
  for (int c = tid; c < cols; c += 256) m = fmaxf(m, row[c]);
  m = bred(red, m, tid, 1);
  float s = 0.f;
  for (int c = tid; c < cols; c += 256){ float e = expf(row[c] - m); row[c] = e; s += e; }
  s = bred(red, s, tid, 0);
  float inv = 1.f/s;
  for (int c = tid; c < cols; c += 256) row[c] *= inv;
}

// ---------------- landmark means ----------------
__global__ __launch_bounds__(256) void landmarks_k(const float* __restrict__ qkv,
                                                   float* __restrict__ ql, float* __restrict__ kl){
  int idx = blockIdx.x*256 + threadIdx.x;
  int d = idx & 63;
  int i = (idx >> 6) & 255;
  int h = (idx >> 14) & 7;
  int b = idx >> 17;
  const float* base = qkv + ((ll)b*NTOK + (ll)i*16)*1536 + h*64 + d;
  float sq = 0.f, sk = 0.f;
  #pragma unroll
  for (int l = 0; l < 16; l++){ sq += base[l*1536]; sk += base[l*1536 + 512]; }
  ql[idx] = sq * (0.125f/16.f);
  kl[idx] = sk * (1.f/16.f);
}

// ---------------- pinv scaling ----------------
__global__ void init_scal_k(unsigned* s){ s[0] = 0u; s[1] = 0u; }

__global__ __launch_bounds__(256) void a2_maxsums_k(const float* __restrict__ a2, unsigned* __restrict__ gm){
  __shared__ float red[256];
  const float* A = a2 + (ll)blockIdx.x*65536;
  int tid = threadIdx.x;
  float cs = 0.f, rs = 0.f;
  for (int i = 0; i < 256; i++) cs += A[i*256 + tid];
  for (int j = 0; j < 256; j++) rs += A[tid*256 + j];
  float cmax = bred(red, cs, tid, 1);
  float rmax = bred(red, rs, tid, 1);
  if (tid == 0){
    atomicMax(gm + 0, __float_as_uint(rmax));
    atomicMax(gm + 1, __float_as_uint(cmax));
  }
}

// z0 = attn2^T / denom
__global__ __launch_bounds__(256) void zinit_k(const float* __restrict__ a2, float* __restrict__ z,
                                               const unsigned* __restrict__ gm){
  float inv = 1.f / (__uint_as_float(gm[0]) * __uint_as_float(gm[1]));
  int idx = blockIdx.x*256 + threadIdx.x;
  int j = idx & 255, i = (idx >> 8) & 255, bh = idx >> 16;
  z[idx] = a2[(ll)bh*65536 + j*256 + i] * inv;
}

// ---------------- depthwise conv ----------------
__global__ __launch_bounds__(256) void dwconv_add_k(const float* __restrict__ qkv,
                                                    const float* __restrict__ cw, float* __restrict__ out){
  __shared__ float sv[160][64];
  __shared__ float w[KCONV];
  int z = blockIdx.y; int b = z >> 3; int h = z & 7;
  int t0 = blockIdx.x * 128;
  int tid = threadIdx.x;
  if (tid < KCONV) w[tid] = cw[h*KCONV + tid];
  const float* vbase = qkv + (ll)b*NTOK*1536 + 1024 + h*64;
  for (int e = tid; e < 160*64; e += 256){
    int r = e >> 6, d = e & 63;
    int t = t0 - 16 + r;
    sv[r][d] = (t >= 0 && t < NTOK) ? vbase[(ll)t*1536 + d] : 0.f;
  }
  __syncthreads();
  float* obase = out + (ll)b*NTOK*512 + h*64;
  for (int e = tid; e < 128*64; e += 256){
    int r = e >> 6, d = e & 63;
    float s = 0.f;
    #pragma unroll
    for (int kk = 0; kk < KCONV; kk++) s += sv[r+kk][d]*w[kk];
    obase[(ll)(t0+r)*512 + d] += s;
  }
}

// ---------------- final head ----------------
__global__ __launch_bounds__(256) void head_k(const float* __restrict__ hb, const float* __restrict__ fns,
      const float* __restrict__ fnb, const float* __restrict__ fw, const float* __restrict__ fb,
      float* __restrict__ out){
  __shared__ float red[256];
  int b = blockIdx.x;
  const float* xr = hb + (ll)b*NTOK*DMODEL;
  int tid = threadIdx.x;
  float v0 = xr[tid], v1 = xr[tid+256];
  float mu = bred(red, v0+v1, tid, 0) * (1.f/512.f);
  float d0 = v0-mu, d1 = v1-mu;
  float var = bred(red, d0*d0 + d1*d1, tid, 0) * (1.f/512.f);
  float inv = 1.f/sqrtf(var + 1e-5f);
  float y0 = d0*inv*fns[tid]     + fnb[tid];
  float y1 = d1*inv*fns[tid+256] + fnb[tid+256];
  float dot = bred(red, y0*fw[tid] + y1*fw[tid+256], tid, 0);
  if (tid == 0){
    float logit = dot + fb[0];
    float prob = 1.f/(1.f + expf(-logit));
    out[b] = logit; out[4+b] = prob; out[8+b] = (prob > 0.5f) ? 1.f : 0.f;
  }
}

// =============================================================================
extern "C" void kernel_launch(void* const* d_in, const int* in_sizes, int n_in,
                              void* d_out, int out_size, void* d_ws, size_t ws_size,
                              hipStream_t stream)
{
  (void)in_sizes; (void)n_in; (void)out_size;
  const float* data  = (const float*)d_in[0];
  const float* fc1_w = (const float*)d_in[1];
  const float* fc1_b = (const float*)d_in[2];
  const float* cls   = (const float*)d_in[3];
  const float* ln_s  = (const float*)d_in[4];
  const float* ln_b  = (const float*)d_in[5];
  const float* qkv_w = (const float*)d_in[6];
  const float* out_w = (const float*)d_in[7];
  const float* out_b = (const float*)d_in[8];
  const float* convw = (const float*)d_in[9];
  const float* fns   = (const float*)d_in[10];
  const float* fnb   = (const float*)d_in[11];
  const float* fcw   = (const float*)d_in[12];
  const float* fcb   = (const float*)d_in[13];
  float* out = (float*)d_out;
  float* ws  = (float*)d_ws;

  float* h   = ws;                   //  8,388,608
  float* x   = h   + 8388608;        //  8,388,608
  float* qkv = x   + 8388608;        // 25,165,824
  float* ql  = qkv + 25165824;       //    524,288
  float* kl  = ql  + 524288;         //    524,288
  float* a2  = kl  + 524288;         //  2,097,152
  float* zA  = a2  + 2097152;        //  2,097,152
  float* zB  = zA  + 2097152;        //  2,097,152
  float* t1  = zB  + 2097152;        //  2,097,152
  float* t2  = t1  + 2097152;        //  2,097,152
  float* t3  = t2  + 2097152;        //  2,097,152
  float* av  = t3  + 2097152;        //    524,288
  float* y2  = av  + 524288;         //    524,288
  unsigned* scal = (unsigned*)(y2 + 524288);
  float* pe = t1;                    // alias (dead before pinv)
  float* po = t1;                    // alias: spans t1+t2 (dead after pinv)
  float* pm = t3;                    // alias
  float* pl = t3 + 65536;            // alias

  const size_t NEED = (size_t)(56623104 + 16) * sizeof(float);
  if (ws_size < NEED) return;

  pe_table_k<<<(TSEQ*DMODEL + 255)/256, 256, 0, stream>>>(pe);
  mgemm<128,128><<<dim3(4, 128, 1), 256, 0, stream>>>(
      data, fc1_w, h, nullptr, fc1_b,
      NBATCH*TSEQ, INDIM, INDIM, DMODEL, DMODEL,
      0, 0, 0, 0.f, 0.f, 1|2|16);
  pe_cls_add_k<<<(NBATCH*NTOK*DMODEL)/256, 256, 0, stream>>>(h, cls, pe);

  for (int L = 0; L < 2; L++){
    const float* qw = qkv_w + (ll)L*DMODEL*1536;
    const float* ow = out_w + (ll)L*DMODEL*DMODEL;
    const float* ob = out_b + (ll)L*DMODEL;
    const float* cw = convw + (ll)L*NHEAD*KCONV;

    ln_rows_k<<<NBATCH*NTOK, 256, 0, stream>>>(h, x, ln_s + L*DMODEL, ln_b + L*DMODEL);
    mgemm<128,128><<<dim3(12, 128, 1), 256, 0, stream>>>(
        x, qw, qkv, nullptr, nullptr,
        NBATCH*NTOK, DMODEL, DMODEL, 1536, 1536,
        0, 0, 0, 0.f, 0.f, 0);
    landmarks_k<<<2048, 256, 0, stream>>>(qkv, ql, kl);

    // attn2 = softmax(ql @ kl^T)  (fp32, feeds pinv scaling)
    gemm_nt<<<dim3(4, 4, NBH), 256, 0, stream>>>(
        ql, kl, a2, 64, 64, 256,
        131072, 16384, 131072, 16384, 524288, 65536, 1.f);
    softmax_rows_k<<<NBH*NLAND, 256, 0, stream>>>(a2, 256);

    init_scal_k<<<1, 1, 0, stream>>>(scal);
    a2_maxsums_k<<<NBH, 256, 0, stream>>>(a2, scal);
    zinit_k<<<8192, 256, 0, stream>>>(a2, zA, scal);

    // Newton-Schulz x6 (bf16 MFMA, z-batched wide launches)
    float* zc = zA; float* zn = zB;
    for (int it = 0; it < 6; it++){
      mgemm<64,64><<<dim3(4, 4, NBH), 256, 0, stream>>>(      // t1 = a2@z
          a2, zc, t1, nullptr, nullptr, 256, 256, 256, 256, 256,
          65536, 65536, 65536, 0.f, 0.f, 0);
      mgemm<64,64><<<dim3(4, 4, NBH), 256, 0, stream>>>(      // t2 = 7t1 - t1@t1
          t1, t1, t2, t1, nullptr, 256, 256, 256, 256, 256,
          65536, 65536, 65536, 7.f, -1.f, 4);
      mgemm<64,64><<<dim3(4, 4, NBH), 256, 0, stream>>>(      // t3 = 15t1 - t1@t2
          t1, t2, t3, t1, nullptr, 256, 256, 256, 256, 256,
          65536, 65536, 65536, 15.f, -1.f, 4);
      mgemm<64,64><<<dim3(4, 4, NBH), 256, 0, stream>>>(      // zn = 3.25z - 0.25 z@t3
          zc, t3, zn, zc, nullptr, 256, 256, 256, 256, 256,
          65536, 65536, 65536, 3.25f, -0.25f, 4);
      float* tmp = zc; zc = zn; zn = tmp;
    }

    // av = softmax(ql @ k^T) @ v  -- MFMA key-split flash + combine
    mflash3_part_k<<<dim3(4, NSPLIT, NBH), 256, 0, stream>>>(
        ql, qkv + 512, qkv + 1024, po, pm, pl,
        64, 1536, 1536,
        131072, 16384, (ll)NTOK*1536, 64, (ll)NTOK*1536, 64);
    flash3_comb_k<<<dim3(64, NBH), 256, 0, stream>>>(po, pm, pl, av);

    // y2 = pinv @ av   (zc holds the converged iterate after 6 swaps)
    mgemm<64,64><<<dim3(1, 4, NBH), 256, 0, stream>>>(
        zc, av, y2, nullptr, nullptr, 256, 256, 256, 64, 64,
        65536, 16384, 16384, 0.f, 0.f, 0);

    // x = softmax(0.125 q @ kl^T) @ y2  (MFMA flash)
    mflash_k<<<dim3(64, 1, NBH), 256, 0, stream>>>(
        qkv, kl, y2, x,
        1536, 64, 64, 512, NLAND, 0.125f,
        (ll)NTOK*1536, 64, 131072, 16384, 131072, 16384, (ll)NTOK*512, 64);

    // x += depthwise_conv(v)
    dwconv_add_k<<<dim3(32, NBH), 256, 0, stream>>>(qkv, cw, x);

    // h = h + x @ out_w + out_b
    mgemm<128,128><<<dim3(4, 128, 1), 256, 0, stream>>>(
        x, ow, h, nullptr, ob,
        NBATCH*NTOK, DMODEL, DMODEL, DMODEL, DMODEL,
        0, 0, 0, 0.f, 0.f, 1|8);
  }

  head_k<<<4, 256, 0, stream>>>(h, fns, fnb, fcw, fcb, out);
}

// Round 6
// 1299.729 us; speedup vs baseline: 3.5397x; 1.2530x over previous
//
#include <hip/hip_runtime.h>
#include <math.h>

typedef long long ll;
typedef __attribute__((ext_vector_type(8))) short short8;
typedef __attribute__((ext_vector_type(4))) float f32x4;

#define NBATCH 4
#define TSEQ   4095
#define NTOK   4096
#define DMODEL 512
#define NHEAD  8
#define DHEAD  64
#define NLAND  256
#define INDIM  1024
#define KCONV  33
#define NBH    32
#define NSPLIT 8

// ---------------- helpers ----------------
__device__ __forceinline__ float bred(float* red, float v, int tid, int op){
  red[tid] = v; __syncthreads();
  for (int s = 128; s > 0; s >>= 1){
    if (tid < s) red[tid] = op ? fmaxf(red[tid], red[tid+s]) : (red[tid] + red[tid+s]);
    __syncthreads();
  }
  float r = red[0];
  __syncthreads();
  return r;
}

__device__ __forceinline__ short f2bf(float f){  // RNE f32->bf16
  unsigned u = __float_as_uint(f);
  u += 0x7fff + ((u>>16)&1);
  return (short)(u>>16);
}
__device__ __forceinline__ float bf2f(short s){
  return __uint_as_float(((unsigned)(unsigned short)s) << 16);
}

// ---------------- PE table ----------------
__global__ __launch_bounds__(256) void pe_table_k(float* __restrict__ pe){
  int idx = blockIdx.x*256 + threadIdx.x;
  if (idx >= TSEQ*DMODEL) return;
  int c = idx & 511; int t = idx >> 9;
  const double NEG = -9.210340371976184 / 512.0;
  double div = exp((double)(c & ~1) * NEG);
  double ang = (double)t * div;
  pe[idx] = (c & 1) ? (float)cos(ang) : (float)sin(ang);
}

__global__ __launch_bounds__(256) void pe_cls_add_k(float* __restrict__ hb, const float* __restrict__ cls,
                                                    const float* __restrict__ pe){
  ll idx = (ll)blockIdx.x*256 + threadIdx.x;
  int c = (int)(idx & 511);
  ll rn = idx >> 9;
  int n = (int)(rn & 4095);
  if (n == 0) hb[idx] = cls[c];
  else        hb[idx] += pe[(ll)(n-1)*512 + c];
}

// ---------------- LayerNorm rows (D=512), fp32 in -> bf16 out ----------------
__global__ __launch_bounds__(256) void ln_rows_k(const float* __restrict__ in, short* __restrict__ out,
                                                 const float* __restrict__ sc, const float* __restrict__ bi){
  __shared__ float red[256];
  ll row = blockIdx.x;
  const float* xr = in + row*DMODEL;
  short* orow = out + row*DMODEL;
  int tid = threadIdx.x;
  float v0 = xr[tid], v1 = xr[tid+256];
  float mu = bred(red, v0+v1, tid, 0) * (1.f/512.f);
  float d0 = v0-mu, d1 = v1-mu;
  float var = bred(red, d0*d0 + d1*d1, tid, 0) * (1.f/512.f);
  float inv = 1.f / sqrtf(var + 1e-5f);
  orow[tid]     = f2bf(d0*inv*sc[tid]     + bi[tid]);
  orow[tid+256] = f2bf(d1*inv*sc[tid+256] + bi[tid+256]);
}

// ============ bf16 MFMA GEMM, templated operand dtypes ============
// AB/BB/CB: 1 = bf16 (short), 0 = fp32.  SW: XCD chunk swizzle.
// flags: 1=+bias[n]  2=relu  4=C=c0*E+c1*acc (E dtype==C dtype)  8=+=C residual  16=fc1 row remap
template<int BM, int BN, int AB, int BB, int CB, int SW>
__global__ __launch_bounds__(256)
void mgemm(const void* __restrict__ Av, const void* __restrict__ Bv,
           void* __restrict__ Cv, const void* __restrict__ Ev,
           const float* __restrict__ bias,
           int Mr, int K, int lda, int ldb, int ldc,
           ll sA, ll sB, ll sC,
           float c0, float c1, int flags)
{
  constexpr int MI = BM/32, NJ = BN/32;
  __shared__ __align__(16) short As[BM*64];
  __shared__ __align__(16) short Bs[BN*64];
  int z = blockIdx.z;
  int bx = blockIdx.x, by = blockIdx.y;
  if (SW){
    int nwg = gridDim.x*gridDim.y;
    int lin = by*gridDim.x + bx;
    int q = nwg >> 3, r = nwg & 7;
    int xcd = lin & 7, idx = lin >> 3;
    int wg = (xcd < r) ? (xcd*(q+1) + idx) : (r*(q+1) + (xcd - r)*q + idx);
    bx = wg % gridDim.x; by = wg / gridDim.x;
  }
  int n0 = bx*BN, m0 = by*BM;
  int tid = threadIdx.x;
  int lane = tid & 63, w = tid >> 6;
  int wr = w >> 1, wc = w & 1;
  int l15 = lane & 15, l4 = lane >> 4;

  f32x4 acc[MI][NJ];
  #pragma unroll
  for (int i = 0; i < MI; i++)
    #pragma unroll
    for (int j = 0; j < NJ; j++) acc[i][j] = (f32x4){0.f,0.f,0.f,0.f};

  for (int k0 = 0; k0 < K; k0 += 64){
    // ---- stage A [BM][64] ----
    #pragma unroll
    for (int it = 0; it < BM/32; ++it){
      int tau = tid + 256*it;
      int row = tau >> 3, slot = tau & 7;
      int grow = m0 + row;
      short8 v;
      if (AB){
        if (grow < Mr) v = *(const short8*)((const short*)Av + (ll)z*sA + (ll)grow*lda + k0 + slot*8);
        else v = (short8){0,0,0,0,0,0,0,0};
      } else {
        f32x4 p0 = {0.f,0.f,0.f,0.f}, p1 = {0.f,0.f,0.f,0.f};
        if (grow < Mr){
          const float* ap = (const float*)Av + (ll)z*sA + (ll)grow*lda + k0 + slot*8;
          p0 = *(const f32x4*)ap; p1 = *(const f32x4*)(ap+4);
        }
        v[0]=f2bf(p0[0]); v[1]=f2bf(p0[1]); v[2]=f2bf(p0[2]); v[3]=f2bf(p0[3]);
        v[4]=f2bf(p1[0]); v[5]=f2bf(p1[1]); v[6]=f2bf(p1[2]); v[7]=f2bf(p1[3]);
      }
      ((short8*)As)[row*8 + (slot ^ (row&7))] = v;
    }
    // ---- stage B transposed: Bs[n][k] <- B[k][n0+n] ----
    #pragma unroll
    for (int it = 0; it < BN/32; ++it){
      int tau = tid + 256*it;
      int n = tau & (BN-1), slot = tau >> (BN==128 ? 7 : 6);
      short8 v;
      if (BB){
        const short* bp = (const short*)Bv + (ll)z*sB + (ll)(k0 + slot*8)*ldb + n0 + n;
        #pragma unroll
        for (int i = 0; i < 8; i++) v[i] = bp[(ll)i*ldb];
      } else {
        const float* bp = (const float*)Bv + (ll)z*sB + (ll)(k0 + slot*8)*ldb + n0 + n;
        #pragma unroll
        for (int i = 0; i < 8; i++) v[i] = f2bf(bp[(ll)i*ldb]);
      }
      ((short8*)Bs)[n*8 + (slot ^ (n&7))] = v;
    }
    __syncthreads();
    #pragma unroll
    for (int kc = 0; kc < 2; kc++){
      short8 af[MI], bfr[NJ];
      #pragma unroll
      for (int i = 0; i < MI; i++){
        int row = wr*(BM/2) + i*16 + l15;
        int g = kc*4 + l4;
        af[i] = ((short8*)As)[row*8 + (g ^ (row&7))];
      }
      #pragma unroll
      for (int j = 0; j < NJ; j++){
        int col = wc*(BN/2) + j*16 + l15;
        int g = kc*4 + l4;
        bfr[j] = ((short8*)Bs)[col*8 + (g ^ (col&7))];
      }
      #pragma unroll
      for (int i = 0; i < MI; i++)
        #pragma unroll
        for (int j = 0; j < NJ; j++)
          acc[i][j] = __builtin_amdgcn_mfma_f32_16x16x32_bf16(af[i], bfr[j], acc[i][j], 0, 0, 0);
    }
    __syncthreads();
  }

  // epilogue
  #pragma unroll
  for (int i = 0; i < MI; i++){
    int rbase = m0 + wr*(BM/2) + i*16 + l4*4;
    #pragma unroll
    for (int j = 0; j < NJ; j++){
      int col = n0 + wc*(BN/2) + j*16 + l15;
      #pragma unroll
      for (int r = 0; r < 4; r++){
        int m = rbase + r;
        if (m >= Mr) continue;
        float v = acc[i][j][r];
        if (flags & 4){
          float ev = CB ? bf2f(((const short*)Ev + (ll)z*sC)[(ll)m*ldc + col])
                        : ((const float*)Ev + (ll)z*sC)[(ll)m*ldc + col];
          v = c0 * ev + c1 * v;
        }
        if (flags & 1) v += bias[col];
        if (flags & 2) v = fmaxf(v, 0.f);
        int om = (flags & 16) ? (m + m/TSEQ + 1) : m;
        ll ci = (ll)z*sC + (ll)om*ldc + col;
        if (CB){
          short* Cs = (short*)Cv;
          if (flags & 8) v += bf2f(Cs[ci]);
          Cs[ci] = f2bf(v);
        } else {
          float* Cf = (float*)Cv;
          if (flags & 8) v += Cf[ci];
          Cf[ci] = v;
        }
      }
    }
  }
}

// ---------------- NT GEMM (attn2 scores: bf16 in, fp32 out) ----------------
__global__ __launch_bounds__(256)
void gemm_nt(const short* __restrict__ A, const short* __restrict__ Bm, float* __restrict__ C,
             int lda, int ldb, int ldc,
             ll sAb, ll sAh, ll sBb, ll sBh, ll sCb, ll sCh,
             float alpha)
{
  __shared__ float As[64][65];
  __shared__ float Bs[64][65];
  int z = blockIdx.z; int b = z >> 3; int h = z & 7;
  A  += (ll)b*sAb + (ll)h*sAh;
  Bm += (ll)b*sBb + (ll)h*sBh;
  C  += (ll)b*sCb + (ll)h*sCh;
  int n0 = blockIdx.x*64, m0 = blockIdx.y*64;
  int tid = threadIdx.x;
  int kk = tid & 63, rr = tid >> 6;
  #pragma unroll
  for (int r = 0; r < 16; r++){
    As[rr + 4*r][kk] = bf2f(A [(ll)(m0 + rr + 4*r)*lda + kk]);
    Bs[rr + 4*r][kk] = bf2f(Bm[(ll)(n0 + rr + 4*r)*ldb + kk]);
  }
  __syncthreads();
  int tx = tid & 15, ty = tid >> 4;
  float acc[4][4] = {};
  for (int k = 0; k < 64; k++){
    float a[4], bv[4];
    #pragma unroll
    for (int i = 0; i < 4; i++) a[i] = As[ty + 16*i][k];
    #pragma unroll
    for (int j = 0; j < 4; j++) bv[j] = Bs[tx + 16*j][k];
    #pragma unroll
    for (int i = 0; i < 4; i++)
      #pragma unroll
      for (int j = 0; j < 4; j++)
        acc[i][j] += a[i]*bv[j];
  }
  #pragma unroll
  for (int i = 0; i < 4; i++)
    #pragma unroll
    for (int j = 0; j < 4; j++)
      C[(ll)(m0 + ty + 16*i)*ldc + n0 + tx + 16*j] = alpha * acc[i][j];
}

// ================= MFMA flash attention, bf16 in (attn1: O bf16 normalized) =================
__global__ __launch_bounds__(256)
void mflash_k(const short* __restrict__ Q, const short* __restrict__ K,
              const short* __restrict__ V, short* __restrict__ O,
              int ldq, int ldk, int ldv, int ldo, int nkeys, float alpha,
              ll sQb, ll sQh, ll sKb, ll sKh, ll sVb, ll sVh, ll sOb, ll sOh)
{
  __shared__ __align__(16) short Qs[64*64];
  __shared__ __align__(16) short Ks[64*64];
  __shared__ __align__(16) short Vs[64*64];
  __shared__ __align__(16) short Ps[64*64];
  __shared__ float Sl[64][68];
  __shared__ float m_l[64], s_l[64], scl[64];
  int z = blockIdx.z; int b = z >> 3; int h = z & 7;
  Q += (ll)b*sQb + (ll)h*sQh;
  K += (ll)b*sKb + (ll)h*sKh;
  V += (ll)b*sVb + (ll)h*sVh;
  O += (ll)b*sOb + (ll)h*sOh;
  int m0 = blockIdx.x*64;
  int tid = threadIdx.x;
  int lane = tid & 63, w = tid >> 6;
  int l15 = lane & 15, l4 = lane >> 4;
  int wr = w >> 1, wc = w & 1;

  #pragma unroll
  for (int it = 0; it < 2; it++){
    int tau = tid + 256*it;
    int row = tau >> 3, slot = tau & 7;
    short8 v = *(const short8*)(Q + (ll)(m0 + row)*ldq + slot*8);
    ((short8*)Qs)[row*8 + (slot ^ (row&7))] = v;
  }
  if (tid < 64){ m_l[tid] = -1e30f; s_l[tid] = 0.f; }
  f32x4 o[2][2];
  #pragma unroll
  for (int i = 0; i < 2; i++)
    #pragma unroll
    for (int j = 0; j < 2; j++) o[i][j] = (f32x4){0.f,0.f,0.f,0.f};

  for (int n0 = 0; n0 < nkeys; n0 += 64){
    __syncthreads();
    #pragma unroll
    for (int it = 0; it < 2; it++){
      int tau = tid + 256*it;
      int row = tau >> 3, slot = tau & 7;
      short8 v = *(const short8*)(K + (ll)(n0 + row)*ldk + slot*8);
      ((short8*)Ks)[row*8 + (slot ^ (row&7))] = v;
    }
    #pragma unroll
    for (int it = 0; it < 2; it++){
      int key = (tid >> 3) + 32*it;
      int d0 = (tid & 7)*8;
      short8 v = *(const short8*)(V + (ll)(n0 + key)*ldv + d0);
      #pragma unroll
      for (int j = 0; j < 8; j++){
        int d = d0 + j;
        Vs[d*64 + (((key>>3) ^ (d&7))<<3) + (key&7)] = v[j];
      }
    }
    __syncthreads();
    // S = Q @ K^T
    f32x4 s[2][2];
    #pragma unroll
    for (int i = 0; i < 2; i++)
      #pragma unroll
      for (int j = 0; j < 2; j++) s[i][j] = (f32x4){0.f,0.f,0.f,0.f};
    #pragma unroll
    for (int kc = 0; kc < 2; kc++){
      short8 aq[2], bk[2];
      int g = kc*4 + l4;
      #pragma unroll
      for (int i = 0; i < 2; i++){
        int row = wr*32 + i*16 + l15;
        aq[i] = ((short8*)Qs)[row*8 + (g ^ (row&7))];
      }
      #pragma unroll
      for (int j = 0; j < 2; j++){
        int key = wc*32 + j*16 + l15;
        bk[j] = ((short8*)Ks)[key*8 + (g ^ (key&7))];
      }
      #pragma unroll
      for (int i = 0; i < 2; i++)
        #pragma unroll
        for (int j = 0; j < 2; j++)
          s[i][j] = __builtin_amdgcn_mfma_f32_16x16x32_bf16(aq[i], bk[j], s[i][j], 0, 0, 0);
    }
    #pragma unroll
    for (int i = 0; i < 2; i++)
      #pragma unroll
      for (int j = 0; j < 2; j++)
        #pragma unroll
        for (int r = 0; r < 4; r++)
          Sl[wr*32 + i*16 + l4*4 + r][wc*32 + j*16 + l15] = s[i][j][r] * alpha;
    __syncthreads();
    // online softmax: 4 threads per row, 16 cols each
    {
      int row = tid >> 2, q = tid & 3, cb = q*16;
      float sv[16];
      float cmax = -1e30f;
      #pragma unroll
      for (int cc = 0; cc < 16; cc++){ sv[cc] = Sl[row][cb+cc]; cmax = fmaxf(cmax, sv[cc]); }
      cmax = fmaxf(cmax, __shfl_xor(cmax, 1));
      cmax = fmaxf(cmax, __shfl_xor(cmax, 2));
      float mprev = m_l[row];
      float newm = fmaxf(mprev, cmax);
      float lsum = 0.f;
      short8 pv0, pv1;
      #pragma unroll
      for (int cc = 0; cc < 8; cc++){ float e = expf(sv[cc]-newm); lsum += e; pv0[cc] = f2bf(e); }
      #pragma unroll
      for (int cc = 0; cc < 8; cc++){ float e = expf(sv[8+cc]-newm); lsum += e; pv1[cc] = f2bf(e); }
      lsum += __shfl_xor(lsum, 1);
      lsum += __shfl_xor(lsum, 2);
      ((short8*)Ps)[row*8 + ((2*q)   ^ (row&7))] = pv0;
      ((short8*)Ps)[row*8 + ((2*q+1) ^ (row&7))] = pv1;
      if (q == 0){
        float scale = expf(mprev - newm);
        m_l[row] = newm;
        s_l[row] = s_l[row]*scale + lsum;
        scl[row] = scale;
      }
    }
    __syncthreads();
    #pragma unroll
    for (int i = 0; i < 2; i++)
      #pragma unroll
      for (int r = 0; r < 4; r++){
        float sc = scl[wr*32 + i*16 + l4*4 + r];
        #pragma unroll
        for (int j = 0; j < 2; j++) o[i][j][r] *= sc;
      }
    #pragma unroll
    for (int kc = 0; kc < 2; kc++){
      short8 ap[2], bv[2];
      int g = kc*4 + l4;
      #pragma unroll
      for (int i = 0; i < 2; i++){
        int row = wr*32 + i*16 + l15;
        ap[i] = ((short8*)Ps)[row*8 + (g ^ (row&7))];
      }
      #pragma unroll
      for (int j = 0; j < 2; j++){
        int d = wc*32 + j*16 + l15;
        bv[j] = ((short8*)Vs)[d*8 + (g ^ (d&7))];
      }
      #pragma unroll
      for (int i = 0; i < 2; i++)
        #pragma unroll
        for (int j = 0; j < 2; j++)
          o[i][j] = __builtin_amdgcn_mfma_f32_16x16x32_bf16(ap[i], bv[j], o[i][j], 0, 0, 0);
    }
  }
  #pragma unroll
  for (int i = 0; i < 2; i++)
    #pragma unroll
    for (int j = 0; j < 2; j++)
      #pragma unroll
      for (int r = 0; r < 4; r++){
        int row = wr*32 + i*16 + l4*4 + r;
        int col = wc*32 + j*16 + l15;
        O[(ll)(m0 + row)*ldo + col] = f2bf(o[i][j][r] / s_l[row]);
      }
}

// ======= MFMA flash attn3 partial (bf16 in; fp32 unnormalized partials) =======
__global__ __launch_bounds__(256)
void mflash3_part_k(const short* __restrict__ Q, const short* __restrict__ K,
                    const short* __restrict__ V,
                    float* __restrict__ po, float* __restrict__ pm, float* __restrict__ pl,
                    int ldq, int ldk, int ldv,
                    ll sQb, ll sQh, ll sKb, ll sKh, ll sVb, ll sVh)
{
  __shared__ __align__(16) short Qs[64*64];
  __shared__ __align__(16) short Ks[64*64];
  __shared__ __align__(16) short Vs[64*64];
  __shared__ __align__(16) short Ps[64*64];
  __shared__ float Sl[64][68];
  __shared__ float m_l[64], s_l[64], scl[64];
  int z = blockIdx.z; int b = z >> 3; int h = z & 7;
  int split = blockIdx.y;
  Q += (ll)b*sQb + (ll)h*sQh;
  K += (ll)b*sKb + (ll)h*sKh;
  V += (ll)b*sVb + (ll)h*sVh;
  int m0 = blockIdx.x*64;
  int koff = split * (NTOK/NSPLIT);
  int tid = threadIdx.x;
  int lane = tid & 63, w = tid >> 6;
  int l15 = lane & 15, l4 = lane >> 4;
  int wr = w >> 1, wc = w & 1;

  #pragma unroll
  for (int it = 0; it < 2; it++){
    int tau = tid + 256*it;
    int row = tau >> 3, slot = tau & 7;
    short8 v = *(const short8*)(Q + (ll)(m0 + row)*ldq + slot*8);
    ((short8*)Qs)[row*8 + (slot ^ (row&7))] = v;
  }
  if (tid < 64){ m_l[tid] = -1e30f; s_l[tid] = 0.f; }
  f32x4 o[2][2];
  #pragma unroll
  for (int i = 0; i < 2; i++)
    #pragma unroll
    for (int j = 0; j < 2; j++) o[i][j] = (f32x4){0.f,0.f,0.f,0.f};

  for (int n0 = koff; n0 < koff + NTOK/NSPLIT; n0 += 64){
    __syncthreads();
    #pragma unroll
    for (int it = 0; it < 2; it++){
      int tau = tid + 256*it;
      int row = tau >> 3, slot = tau & 7;
      short8 v = *(const short8*)(K + (ll)(n0 + row)*ldk + slot*8);
      ((short8*)Ks)[row*8 + (slot ^ (row&7))] = v;
    }
    #pragma unroll
    for (int it = 0; it < 2; it++){
      int key = (tid >> 3) + 32*it;
      int d0 = (tid & 7)*8;
      short8 v = *(const short8*)(V + (ll)(n0 + key)*ldv + d0);
      #pragma unroll
      for (int j = 0; j < 8; j++){
        int d = d0 + j;
        Vs[d*64 + (((key>>3) ^ (d&7))<<3) + (key&7)] = v[j];
      }
    }
    __syncthreads();
    f32x4 s[2][2];
    #pragma unroll
    for (int i = 0; i < 2; i++)
      #pragma unroll
      for (int j = 0; j < 2; j++) s[i][j] = (f32x4){0.f,0.f,0.f,0.f};
    #pragma unroll
    for (int kc = 0; kc < 2; kc++){
      short8 aq[2], bk[2];
      int g = kc*4 + l4;
      #pragma unroll
      for (int i = 0; i < 2; i++){
        int row = wr*32 + i*16 + l15;
        aq[i] = ((short8*)Qs)[row*8 + (g ^ (row&7))];
      }
      #pragma unroll
      for (int j = 0; j < 2; j++){
        int key = wc*32 + j*16 + l15;
        bk[j] = ((short8*)Ks)[key*8 + (g ^ (key&7))];
      }
      #pragma unroll
      for (int i = 0; i < 2; i++)
        #pragma unroll
        for (int j = 0; j < 2; j++)
          s[i][j] = __builtin_amdgcn_mfma_f32_16x16x32_bf16(aq[i], bk[j], s[i][j], 0, 0, 0);
    }
    #pragma unroll
    for (int i = 0; i < 2; i++)
      #pragma unroll
      for (int j = 0; j < 2; j++)
        #pragma unroll
        for (int r = 0; r < 4; r++)
          Sl[wr*32 + i*16 + l4*4 + r][wc*32 + j*16 + l15] = s[i][j][r];
    __syncthreads();
    {
      int row = tid >> 2, q = tid & 3, cb = q*16;
      float sv[16];
      float cmax = -1e30f;
      #pragma unroll
      for (int cc = 0; cc < 16; cc++){ sv[cc] = Sl[row][cb+cc]; cmax = fmaxf(cmax, sv[cc]); }
      cmax = fmaxf(cmax, __shfl_xor(cmax, 1));
      cmax = fmaxf(cmax, __shfl_xor(cmax, 2));
      float mprev = m_l[row];
      float newm = fmaxf(mprev, cmax);
      float lsum = 0.f;
      short8 pv0, pv1;
      #pragma unroll
      for (int cc = 0; cc < 8; cc++){ float e = expf(sv[cc]-newm); lsum += e; pv0[cc] = f2bf(e); }
      #pragma unroll
      for (int cc = 0; cc < 8; cc++){ float e = expf(sv[8+cc]-newm); lsum += e; pv1[cc] = f2bf(e); }
      lsum += __shfl_xor(lsum, 1);
      lsum += __shfl_xor(lsum, 2);
      ((short8*)Ps)[row*8 + ((2*q)   ^ (row&7))] = pv0;
      ((short8*)Ps)[row*8 + ((2*q+1) ^ (row&7))] = pv1;
      if (q == 0){
        float scale = expf(mprev - newm);
        m_l[row] = newm;
        s_l[row] = s_l[row]*scale + lsum;
        scl[row] = scale;
      }
    }
    __syncthreads();
    #pragma unroll
    for (int i = 0; i < 2; i++)
      #pragma unroll
      for (int r = 0; r < 4; r++){
        float sc = scl[wr*32 + i*16 + l4*4 + r];
        #pragma unroll
        for (int j = 0; j < 2; j++) o[i][j][r] *= sc;
      }
    #pragma unroll
    for (int kc = 0; kc < 2; kc++){
      short8 ap[2], bv[2];
      int g = kc*4 + l4;
      #pragma unroll
      for (int i = 0; i < 2; i++){
        int row = wr*32 + i*16 + l15;
        ap[i] = ((short8*)Ps)[row*8 + (g ^ (row&7))];
      }
      #pragma unroll
      for (int j = 0; j < 2; j++){
        int d = wc*32 + j*16 + l15;
        bv[j] = ((short8*)Vs)[d*8 + (g ^ (d&7))];
      }
      #pragma unroll
      for (int i = 0; i < 2; i++)
        #pragma unroll
        for (int j = 0; j < 2; j++)
          o[i][j] = __builtin_amdgcn_mfma_f32_16x16x32_bf16(ap[i], bv[j], o[i][j], 0, 0, 0);
    }
  }
  int bs = z*NSPLIT + split;
  #pragma unroll
  for (int i = 0; i < 2; i++)
    #pragma unroll
    for (int j = 0; j < 2; j++)
      #pragma unroll
      for (int r = 0; r < 4; r++){
        int row = wr*32 + i*16 + l4*4 + r;
        int col = wc*32 + j*16 + l15;
        po[((ll)bs*NLAND + m0 + row)*64 + col] = o[i][j][r];
      }
  if (tid < 64){
    pm[(ll)bs*NLAND + m0 + tid] = m_l[tid];
    pl[(ll)bs*NLAND + m0 + tid] = s_l[tid];
  }
}

// combine splits -> av[bh][row][64] (bf16)
__global__ __launch_bounds__(256)
void flash3_comb_k(const float* __restrict__ po, const float* __restrict__ pm,
                   const float* __restrict__ pl, short* __restrict__ av){
  int bh = blockIdx.y;
  int row = blockIdx.x*4 + (threadIdx.x >> 6);
  int col = threadIdx.x & 63;
  float ms = -1e30f;
  float mv[NSPLIT];
  #pragma unroll
  for (int s = 0; s < NSPLIT; s++){
    mv[s] = pm[((ll)bh*NSPLIT + s)*NLAND + row];
    ms = fmaxf(ms, mv[s]);
  }
  float osum = 0.f, lsum = 0.f;
  #pragma unroll
  for (int s = 0; s < NSPLIT; s++){
    float wgt = expf(mv[s] - ms);
    osum += wgt * po[(((ll)bh*NSPLIT + s)*NLAND + row)*64 + col];
    lsum += wgt * pl[((ll)bh*NSPLIT + s)*NLAND + row];
  }
  av[((ll)bh*NLAND + row)*64 + col] = f2bf(osum / lsum);
}

// ---------------- row softmax (fp32 in-place; optional bf16 copy) ----------------
__global__ __launch_bounds__(256) void softmax_rows_k(float* __restrict__ data, short* __restrict__ out16,
                                                      int cols){
  __shared__ float red[256];
  float* row = data + (ll)blockIdx.x * cols;
  short* row16 = out16 ? out16 + (ll)blockIdx.x * cols : nullptr;
  int tid = threadIdx.x;
  float m = -1e30f;
  for (int c = tid; c < cols; c += 256) m = fmaxf(m, row[c]);
  m = bred(red, m, tid, 1);
  float s = 0.f;
  for (int c = tid; c < cols; c += 256){ float e = expf(row[c] - m); row[c] = e; s += e; }
  s = bred(red, s, tid, 0);
  float inv = 1.f/s;
  for (int c = tid; c < cols; c += 256){
    float p = row[c] * inv;
    row[c] = p;
    if (row16) row16[c] = f2bf(p);
  }
}

// ---------------- landmark means (bf16 in, bf16 out; q scaled by 1/8) ----------------
__global__ __launch_bounds__(256) void landmarks_k(const short* __restrict__ qkv,
                                                   short* __restrict__ ql, short* __restrict__ kl){
  int idx = blockIdx.x*256 + threadIdx.x;
  int d = idx & 63;
  int i = (idx >> 6) & 255;
  int h = (idx >> 14) & 7;
  int b = idx >> 17;
  const short* base = qkv + ((ll)b*NTOK + (ll)i*16)*1536 + h*64 + d;
  float sq = 0.f, sk = 0.f;
  #pragma unroll
  for (int l = 0; l < 16; l++){ sq += bf2f(base[l*1536]); sk += bf2f(base[l*1536 + 512]); }
  ql[idx] = f2bf(sq * (0.125f/16.f));
  kl[idx] = f2bf(sk * (1.f/16.f));
}

// ---------------- pinv scaling ----------------
__global__ void init_scal_k(unsigned* s){ s[0] = 0u; s[1] = 0u; }

__global__ __launch_bounds__(256) void a2_maxsums_k(const float* __restrict__ a2, unsigned* __restrict__ gm){
  __shared__ float red[256];
  const float* A = a2 + (ll)blockIdx.x*65536;
  int tid = threadIdx.x;
  float cs = 0.f, rs = 0.f;
  for (int i = 0; i < 256; i++) cs += A[i*256 + tid];
  for (int j = 0; j < 256; j++) rs += A[tid*256 + j];
  float cmax = bred(red, cs, tid, 1);
  float rmax = bred(red, rs, tid, 1);
  if (tid == 0){
    atomicMax(gm + 0, __float_as_uint(rmax));
    atomicMax(gm + 1, __float_as_uint(cmax));
  }
}

// z0 = attn2^T / denom  (bf16 out)
__global__ __launch_bounds__(256) void zinit_k(const float* __restrict__ a2, short* __restrict__ z,
                                               const unsigned* __restrict__ gm){
  float inv = 1.f / (__uint_as_float(gm[0]) * __uint_as_float(gm[1]));
  int idx = blockIdx.x*256 + threadIdx.x;
  int j = idx & 255, i = (idx >> 8) & 255, bh = idx >> 16;
  z[idx] = f2bf(a2[(ll)bh*65536 + j*256 + i] * inv);
}

// ---------------- depthwise conv (bf16 v in, += into bf16 out) ----------------
__global__ __launch_bounds__(256) void dwconv_add_k(const short* __restrict__ qkv,
                                                    const float* __restrict__ cw, short* __restrict__ out){
  __shared__ float sv[160][64];
  __shared__ float w[KCONV];
  int z = blockIdx.y; int b = z >> 3; int h = z & 7;
  int t0 = blockIdx.x * 128;
  int tid = threadIdx.x;
  if (tid < KCONV) w[tid] = cw[h*KCONV + tid];
  const short* vbase = qkv + (ll)b*NTOK*1536 + 1024 + h*64;
  for (int e = tid; e < 160*64; e += 256){
    int r = e >> 6, d = e & 63;
    int t = t0 - 16 + r;
    sv[r][d] = (t >= 0 && t < NTOK) ? bf2f(vbase[(ll)t*1536 + d]) : 0.f;
  }
  __syncthreads();
  short* obase = out + (ll)b*NTOK*512 + h*64;
  for (int e = tid; e < 128*64; e += 256){
    int r = e >> 6, d = e & 63;
    float s = 0.f;
    #pragma unroll
    for (int kk = 0; kk < KCONV; kk++) s += sv[r+kk][d]*w[kk];
    ll oi = (ll)(t0+r)*512 + d;
    obase[oi] = f2bf(bf2f(obase[oi]) + s);
  }
}

// ---------------- final head ----------------
__global__ __launch_bounds__(256) void head_k(const float* __restrict__ hb, const float* __restrict__ fns,
      const float* __restrict__ fnb, const float* __restrict__ fw, const float* __restrict__ fb,
      float* __restrict__ out){
  __shared__ float red[256];
  int b = blockIdx.x;
  const float* xr = hb + (ll)b*NTOK*DMODEL;
  int tid = threadIdx.x;
  float v0 = xr[tid], v1 = xr[tid+256];
  float mu = bred(red, v0+v1, tid, 0) * (1.f/512.f);
  float d0 = v0-mu, d1 = v1-mu;
  float var = bred(red, d0*d0 + d1*d1, tid, 0) * (1.f/512.f);
  float inv = 1.f/sqrtf(var + 1e-5f);
  float y0 = d0*inv*fns[tid]     + fnb[tid];
  float y1 = d1*inv*fns[tid+256] + fnb[tid+256];
  float dot = bred(red, y0*fw[tid] + y1*fw[tid+256], tid, 0);
  if (tid == 0){
    float logit = dot + fb[0];
    float prob = 1.f/(1.f + expf(-logit));
    out[b] = logit; out[4+b] = prob; out[8+b] = (prob > 0.5f) ? 1.f : 0.f;
  }
}

// =============================================================================
extern "C" void kernel_launch(void* const* d_in, const int* in_sizes, int n_in,
                              void* d_out, int out_size, void* d_ws, size_t ws_size,
                              hipStream_t stream)
{
  (void)in_sizes; (void)n_in; (void)out_size;
  const float* data  = (const float*)d_in[0];
  const float* fc1_w = (const float*)d_in[1];
  const float* fc1_b = (const float*)d_in[2];
  const float* cls   = (const float*)d_in[3];
  const float* ln_s  = (const float*)d_in[4];
  const float* ln_b  = (const float*)d_in[5];
  const float* qkv_w = (const float*)d_in[6];
  const float* out_w = (const float*)d_in[7];
  const float* out_b = (const float*)d_in[8];
  const float* convw = (const float*)d_in[9];
  const float* fns   = (const float*)d_in[10];
  const float* fnb   = (const float*)d_in[11];
  const float* fcw   = (const float*)d_in[12];
  const float* fcb   = (const float*)d_in[13];
  float* out = (float*)d_out;
  float* ws  = (float*)d_ws;

  // ---- workspace layout: fp32 residual/stats, bf16 activations ----
  float* h    = ws;                                   // 8,388,608 f
  short* xb   = (short*)(h + 8388608);                // 8,388,608 s  (LN out / attn out)
  short* qkvh = xb + 8388608;                         // 25,165,824 s
  short* ql   = qkvh + 25165824;                      //   524,288 s
  short* kl   = ql + 524288;                          //   524,288 s
  float* a2f  = (float*)(kl + 524288);                // 2,097,152 f
  short* a2h  = (short*)(a2f + 2097152);              // 2,097,152 s
  short* zA   = a2h + 2097152;                        // 2,097,152 s
  short* zB   = zA + 2097152;                         // 2,097,152 s
  short* t1   = zB + 2097152;                         // 2,097,152 s
  short* t2   = t1 + 2097152;                         // 2,097,152 s
  short* t3   = t2 + 2097152;                         // 2,097,152 s
  short* av   = t3 + 2097152;                         //   524,288 s
  short* y2   = av + 524288;                          //   524,288 s
  float* po   = (float*)(y2 + 524288);                // 4,194,304 f
  float* pm   = po + 4194304;                         //    65,536 f
  float* pl   = pm + 65536;                           //    65,536 f
  float* pe   = pl + 65536;                           // 2,097,152 f
  unsigned* scal = (unsigned*)(pe + 2097152);

  const size_t NEED = (size_t)((char*)(scal + 2) - (char*)ws);
  if (ws_size < NEED) return;

  pe_table_k<<<(TSEQ*DMODEL + 255)/256, 256, 0, stream>>>(pe);
  // fc1 (fp32 A/B -> fp32 h, remap rows, +bias, relu)
  mgemm<128,128,0,0,0,1><<<dim3(4, 128, 1), 256, 0, stream>>>(
      data, fc1_w, h, nullptr, fc1_b,
      NBATCH*TSEQ, INDIM, INDIM, DMODEL, DMODEL,
      0, 0, 0, 0.f, 0.f, 1|2|16);
  pe_cls_add_k<<<(NBATCH*NTOK*DMODEL)/256, 256, 0, stream>>>(h, cls, pe);

  for (int L = 0; L < 2; L++){
    const float* qw = qkv_w + (ll)L*DMODEL*1536;
    const float* ow = out_w + (ll)L*DMODEL*DMODEL;
    const float* ob = out_b + (ll)L*DMODEL;
    const float* cw = convw + (ll)L*NHEAD*KCONV;

    ln_rows_k<<<NBATCH*NTOK, 256, 0, stream>>>(h, xb, ln_s + L*DMODEL, ln_b + L*DMODEL);
    // qkv = xb @ qkv_w  (bf16 A, fp32 B -> bf16 out)
    mgemm<128,128,1,0,1,1><<<dim3(12, 128, 1), 256, 0, stream>>>(
        xb, qw, qkvh, nullptr, nullptr,
        NBATCH*NTOK, DMODEL, DMODEL, 1536, 1536,
        0, 0, 0, 0.f, 0.f, 0);
    landmarks_k<<<2048, 256, 0, stream>>>(qkvh, ql, kl);

    // attn2 scores fp32 + softmax (writes fp32 a2f + bf16 a2h)
    gemm_nt<<<dim3(4, 4, NBH), 256, 0, stream>>>(
        ql, kl, a2f, 64, 64, 256,
        131072, 16384, 131072, 16384, 524288, 65536, 1.f);
    softmax_rows_k<<<NBH*NLAND, 256, 0, stream>>>(a2f, a2h, 256);

    init_scal_k<<<1, 1, 0, stream>>>(scal);
    a2_maxsums_k<<<NBH, 256, 0, stream>>>(a2f, scal);
    zinit_k<<<8192, 256, 0, stream>>>(a2f, zA, scal);

    // Newton-Schulz x6, all-bf16 storage
    short* zc = zA; short* zn = zB;
    for (int it = 0; it < 6; it++){
      mgemm<64,64,1,1,1,0><<<dim3(4, 4, NBH), 256, 0, stream>>>(   // t1 = a2@z
          a2h, zc, t1, nullptr, nullptr, 256, 256, 256, 256, 256,
          65536, 65536, 65536, 0.f, 0.f, 0);
      mgemm<64,64,1,1,1,0><<<dim3(4, 4, NBH), 256, 0, stream>>>(   // t2 = 7t1 - t1@t1
          t1, t1, t2, t1, nullptr, 256, 256, 256, 256, 256,
          65536, 65536, 65536, 7.f, -1.f, 4);
      mgemm<64,64,1,1,1,0><<<dim3(4, 4, NBH), 256, 0, stream>>>(   // t3 = 15t1 - t1@t2
          t1, t2, t3, t1, nullptr, 256, 256, 256, 256, 256,
          65536, 65536, 65536, 15.f, -1.f, 4);
      mgemm<64,64,1,1,1,0><<<dim3(4, 4, NBH), 256, 0, stream>>>(   // zn = 3.25z - 0.25 z@t3
          zc, t3, zn, zc, nullptr, 256, 256, 256, 256, 256,
          65536, 65536, 65536, 3.25f, -0.25f, 4);
      short* tmp = zc; zc = zn; zn = tmp;
    }

    // av = softmax(ql @ k^T) @ v  (key-split MFMA flash + combine)
    mflash3_part_k<<<dim3(4, NSPLIT, NBH), 256, 0, stream>>>(
        ql, qkvh + 512, qkvh + 1024, po, pm, pl,
        64, 1536, 1536,
        131072, 16384, (ll)NTOK*1536, 64, (ll)NTOK*1536, 64);
    flash3_comb_k<<<dim3(64, NBH), 256, 0, stream>>>(po, pm, pl, av);

    // y2 = pinv @ av  (all bf16)
    mgemm<64,64,1,1,1,0><<<dim3(1, 4, NBH), 256, 0, stream>>>(
        zc, av, y2, nullptr, nullptr, 256, 256, 256, 64, 64,
        65536, 16384, 16384, 0.f, 0.f, 0);

    // xb = softmax(0.125 q @ kl^T) @ y2  (attn1; alpha applied to scores)
    mflash_k<<<dim3(64, 1, NBH), 256, 0, stream>>>(
        qkvh, kl, y2, xb,
        1536, 64, 64, 512, NLAND, 0.125f,
        (ll)NTOK*1536, 64, 131072, 16384, 131072, 16384, (ll)NTOK*512, 64);

    // xb += depthwise_conv(v)
    dwconv_add_k<<<dim3(32, NBH), 256, 0, stream>>>(qkvh, cw, xb);

    // h = h + xb @ out_w + out_b  (bf16 A, fp32 B -> fp32 h residual)
    mgemm<128,128,1,0,0,1><<<dim3(4, 128, 1), 256, 0, stream>>>(
        xb, ow, h, nullptr, ob,
        NBATCH*NTOK, DMODEL, DMODEL, DMODEL, DMODEL,
        0, 0, 0, 0.f, 0.f, 1|8);
  }

  head_k<<<4, 256, 0, stream>>>(h, fns, fnb, fcw, fcb, out);
}